// Round 3
// baseline (3599.802 us; speedup 1.0000x reference)
//
#include <hip/hip_runtime.h>
#include <cstdint>
#include <cstddef>

// ---------------------------------------------------------------------------
// MultiLayerAttentionModel on MI355X (gfx950), bf16 MFMA pipeline, round 10.
// Round 9 + k_qkv8 restructured: one barrier per phase, fragment ds_reads
// software-pipelined one phase ahead (issued right after MFMA issue, drain in
// LDS pipe while matrix pipe executes). Phase: [STAGE|lgkm0|vmcnt4|bar|MFMA|
// ds_read next-phase frags]. B0 frags double-buffered by tile parity (b0a/b0b,
// 2-tile unrolled loop). 24 ds_read_b128 per wave-tile (B0 retained).
// ---------------------------------------------------------------------------

typedef unsigned short u16;
typedef float f32x4 __attribute__((ext_vector_type(4)));
typedef unsigned short u16x8 __attribute__((ext_vector_type(8)));

#define P 576
#define NQK 1664
#define VTROWS 514
#define KVLD 640

__device__ __forceinline__ float bf2f(u16 s) {
    union { unsigned u; float f; } v; v.u = ((unsigned)s) << 16; return v.f;
}
__device__ __forceinline__ u16 f2bf(float f) {
    union { float f; unsigned u; } v; v.f = f;
    unsigned r = v.u + 0x7FFF + ((v.u >> 16) & 1);
    return (u16)(r >> 16);
}
__device__ __forceinline__ float wredsum(float v) {
#pragma unroll
    for (int o = 32; o > 0; o >>= 1) v += __shfl_xor(v, o, 64);
    return v;
}
__device__ __forceinline__ f32x4 mfma_16x16x32_bf16(u16x8 a, u16x8 b, f32x4 c) {
    asm volatile("v_mfma_f32_16x16x32_bf16 %0, %1, %2, %0"
                 : "+v"(c) : "v"(a), "v"(b));
    return c;
}
__device__ __forceinline__ void gload_lds16(const u16* g, u16* l) {
    __builtin_amdgcn_global_load_lds(
        (const __attribute__((address_space(1))) void*)g,
        (__attribute__((address_space(3))) void*)l, 16, 0, 0);
}

// ---------------------------------------------------------------------------
__global__ __launch_bounds__(256) void k_build_tokens(
    const float* __restrict__ xs, const float* __restrict__ ys,
    const float* __restrict__ qx, u16* __restrict__ tok,
    float* __restrict__ meanb, float* __restrict__ rstdb)
{
    long row = (long)blockIdx.x * 4 + (threadIdx.x >> 6);
    int lane = threadIdx.x & 63;
    int b = (int)(row >> 11), n = (int)(row & 2047);
    const float* src = (n < 2047) ? xs + ((long)(b * 2047 + n)) * 512
                                  : qx + (long)b * 512;
    float4 f0 = *(const float4*)(src + lane * 8);
    float4 f1 = *(const float4*)(src + lane * 8 + 4);
    float y = (n < 2047) ? ys[(long)b * 2047 + n] : 0.f;
    float v[8] = {f0.x, f0.y, f0.z, f0.w, f1.x, f1.y, f1.z, f1.w};
    float s = 0.f, sq = 0.f;
#pragma unroll
    for (int j = 0; j < 8; j++) { s += v[j]; sq += v[j] * v[j]; }
    if (lane == 0) { s += y; sq += y * y; }
    s = wredsum(s); sq = wredsum(sq);
    u16x8 o;
#pragma unroll
    for (int j = 0; j < 8; j++) o[j] = f2bf(v[j]);
    *(u16x8*)(tok + row * P + lane * 8) = o;
    if (lane < 8) {
        u16x8 z8 = {0,0,0,0,0,0,0,0};
        if (lane == 0) z8[0] = f2bf(y);
        *(u16x8*)(tok + row * P + 512 + lane * 8) = z8;
    }
    if (lane == 0) {
        float m = s * (1.f / 513.f);
        float var = sq * (1.f / 513.f) - m * m;
        meanb[row] = m;
        rstdb[row] = 1.f / sqrtf(var + 1e-5f);
    }
}

__global__ __launch_bounds__(256) void k_prep_wcat(
    const float* __restrict__ wq, const float* __restrict__ wk,
    const float* __restrict__ wv, const float* __restrict__ ln1w,
    u16* __restrict__ wcat)
{
    long idx = (long)blockIdx.x * 256 + threadIdx.x;
    if (idx >= 4L * NQK * P) return;
    int t = (int)(idx % P);
    long rem = idx / P;
    int r = (int)(rem % NQK);
    int l = (int)(rem / NQK);
    float v = 0.f;
    if (t < 513) {
        float wsc = ln1w[l * 513 + t];
        if (r < 512)       v = wq[((long)l * 512 + r) * 513 + t] * wsc;
        else if (r < 1024) v = wk[((long)l * 512 + (r - 512)) * 513 + t] * wsc;
        else if (r < 1537) v = wv[((long)l * 513 + (r - 1024)) * 513 + t] * wsc;
    }
    wcat[idx] = f2bf(v);
}

__global__ __launch_bounds__(256) void k_prep_wo(
    const float* __restrict__ wo, u16* __restrict__ wop)
{
    long idx = (long)blockIdx.x * 256 + threadIdx.x;
    if (idx >= 4L * P * P) return;
    int u = (int)(idx % P);
    long rem = idx / P;
    int t = (int)(rem % P);
    int l = (int)(rem / P);
    float v = (t < 513 && u < 513) ? wo[((long)l * 513 + t) * 513 + u] : 0.f;
    wop[idx] = f2bf(v);
}

__global__ __launch_bounds__(256) void k_prep_sums(
    const float* __restrict__ wq, const float* __restrict__ wk,
    const float* __restrict__ wv, const float* __restrict__ ln1w,
    const float* __restrict__ ln1b, float* __restrict__ s1, float* __restrict__ s2)
{
    int id = blockIdx.x * 4 + (threadIdx.x >> 6);
    int lane = threadIdx.x & 63;
    int l = id / NQK, r = id % NQK;
    float a1 = 0.f, a2 = 0.f;
    for (int t = lane; t < 513; t += 64) {
        float wc = 0.f;
        if (r < 512)       wc = wq[((long)l * 512 + r) * 513 + t];
        else if (r < 1024) wc = wk[((long)l * 512 + (r - 512)) * 513 + t];
        else if (r < 1537) wc = wv[((long)l * 513 + (r - 1024)) * 513 + t];
        a1 += ln1w[l * 513 + t] * wc;
        a2 += ln1b[l * 513 + t] * wc;
    }
    a1 = wredsum(a1); a2 = wredsum(a2);
    if (lane == 0) { s1[id] = a1; s2[id] = a2; }
}

// ---------------------------------------------------------------------------
__global__ __launch_bounds__(256) void k_ln2(
    const u16* __restrict__ z, u16* __restrict__ tok,
    const float* __restrict__ w, const float* __restrict__ bia,
    float* __restrict__ meanb, float* __restrict__ rstdb)
{
    long row = (long)blockIdx.x * 4 + (threadIdx.x >> 6);
    int lane = threadIdx.x & 63;
    const u16* zp = z + row * P;
    u16* tp = tok + row * P;
    u16x8 a0 = *(const u16x8*)(zp + lane * 8);
    u16x8 a1 = {0,0,0,0,0,0,0,0};
    if (lane < 8) a1 = *(const u16x8*)(zp + 512 + lane * 8);
    float v0[8], v1[8];
#pragma unroll
    for (int j = 0; j < 8; j++) v0[j] = bf2f(a0[j]);
#pragma unroll
    for (int j = 0; j < 8; j++) v1[j] = (lane < 8) ? bf2f(a1[j]) : 0.f;
    float s = 0.f, sq = 0.f;
#pragma unroll
    for (int j = 0; j < 8; j++) { s += v0[j]; sq += v0[j] * v0[j]; }
#pragma unroll
    for (int j = 0; j < 8; j++) { s += v1[j]; sq += v1[j] * v1[j]; }
    s = wredsum(s); sq = wredsum(sq);
    float mean = s * (1.f / 513.f);
    float var = sq * (1.f / 513.f) - mean * mean;
    float rstd = 1.f / sqrtf(var + 1e-5f);
    float so = 0.f, so2 = 0.f;
    u16x8 o0;
    float of0[8];
#pragma unroll
    for (int j = 0; j < 8; j++) {
        int t = lane * 8 + j;
        of0[j] = (v0[j] - mean) * rstd * w[t] + bia[t];
        so += of0[j]; so2 += of0[j] * of0[j];
        o0[j] = f2bf(of0[j]);
    }
    float of1[8];
#pragma unroll
    for (int j = 0; j < 8; j++) {
        int t = 512 + lane * 8 + j;
        float ov = 0.f;
        if (lane < 8 && t < 513) ov = (v1[j] - mean) * rstd * w[t] + bia[t];
        of1[j] = ov;
        so += ov; so2 += ov * ov;
    }
    so = wredsum(so); so2 = wredsum(so2);
    *(u16x8*)(tp + lane * 8) = o0;
    if (lane < 8) {
        u16x8 o1;
#pragma unroll
        for (int j = 0; j < 8; j++) o1[j] = f2bf(of1[j]);
        *(u16x8*)(tp + 512 + lane * 8) = o1;
    }
    if (lane == 0) {
        float m2 = so * (1.f / 513.f);
        float v2 = so2 * (1.f / 513.f) - m2 * m2;
        meanb[row] = m2;
        rstdb[row] = 1.f / sqrtf(v2 + 1e-5f);
    }
}

// ---------------------------------------------------------------------------
__global__ __launch_bounds__(256) void k_qknorm(
    u16* __restrict__ qkv, float* __restrict__ rkout,
    const float* __restrict__ scale, int l)
{
    long row = (long)blockIdx.x * 4 + (threadIdx.x >> 6);
    int lane = threadIdx.x & 63;
    float s = log1pf(expf(scale[l]));
    u16* rowp = qkv + row * NQK;
    u16x8 q8 = *(const u16x8*)(rowp + lane * 8);
    u16x8 k8 = *(const u16x8*)(rowp + 512 + lane * 8);
    float qf[8];
    float sqv = 0.f, skv = 0.f;
#pragma unroll
    for (int j = 0; j < 8; j++) { qf[j] = bf2f(q8[j]); sqv += qf[j] * qf[j]; }
#pragma unroll
    for (int j = 0; j < 8; j++) { float kf = bf2f(k8[j]); skv += kf * kf; }
    sqv = wredsum(sqv); skv = wredsum(skv);
    float rnq = 1.f / fmaxf(sqrtf(sqv), 1e-12f);
    float rnk = 1.f / fmaxf(sqrtf(skv), 1e-12f);
    u16x8 o;
#pragma unroll
    for (int j = 0; j < 8; j++) {
        float q = qf[j] * rnq;
        float qp = (q > 0.f) ? (q + 1.f) : expf(q);
        o[j] = f2bf(qp * s);
    }
    *(u16x8*)(rowp + lane * 8) = o;
    if (lane == 0) rkout[row] = rnk;
}

// ---------------------------------------------------------------------------
// K-section transpose only: ct in 0..7 -> kpt[b][h][n] with elu(K*rk)+1.
__global__ __launch_bounds__(256) void k_trans(
    const u16* __restrict__ qkv, const float* __restrict__ rk,
    u16* __restrict__ kpt)
{
    int ct = blockIdx.x;
    long r0 = (long)blockIdx.y * 64;
    int b = (int)(r0 >> 11);
    int nloc = (int)(r0 & 2047);
    int tid = threadIdx.x;
    int r = tid >> 2;
    int c0 = (tid & 3) * 16;
    __shared__ u16 T[64 * 80];
    const u16* src = qkv + (r0 + r) * NQK + 512 + ct * 64 + c0;
    u16x8 a = *(const u16x8*)src;
    u16x8 d = *(const u16x8*)(src + 8);
    float rkv = rk[r0 + r];
#pragma unroll
    for (int j = 0; j < 8; j++) {
        float kv = bf2f(a[j]) * rkv; kv = (kv > 0.f) ? kv + 1.f : expf(kv);
        T[(c0 + j) * 80 + r] = f2bf(kv);
    }
#pragma unroll
    for (int j = 0; j < 8; j++) {
        float kv = bf2f(d[j]) * rkv; kv = (kv > 0.f) ? kv + 1.f : expf(kv);
        T[(c0 + 8 + j) * 80 + r] = f2bf(kv);
    }
    __syncthreads();
    int orow = tid >> 2;
    int oc0 = (tid & 3) * 16;
    u16x8 w0 = *(const u16x8*)&T[orow * 80 + oc0];
    u16x8 w1 = *(const u16x8*)&T[orow * 80 + oc0 + 8];
    u16* dst = kpt + ((long)b * 512 + ct * 64 + orow) * 2048 + nloc + oc0;
    *(u16x8*)dst = w0;
    *(u16x8*)(dst + 8) = w1;
}

// ---------------------------------------------------------------------------
__global__ __launch_bounds__(512) void k_extract_ksum(
    const u16* __restrict__ kvh, float* __restrict__ ksum)
{
    int b = blockIdx.x, h = threadIdx.x;
    ksum[(long)b * 512 + h] = bf2f(kvh[((long)b * 512 + h) * KVLD + 513]);
}

__global__ __launch_bounds__(256) void k_denom(
    const u16* __restrict__ qkv, const float* __restrict__ ksum,
    float* __restrict__ denom)
{
    long row = (long)blockIdx.x * 4 + (threadIdx.x >> 6);
    int lane = threadIdx.x & 63;
    int b = (int)(row >> 11);
    u16x8 q = *(const u16x8*)(qkv + row * NQK + lane * 8);
    const float* ks = ksum + (long)b * 512 + lane * 8;
    float acc = 0.f;
#pragma unroll
    for (int j = 0; j < 8; j++) acc += bf2f(q[j]) * ks[j];
    acc = wredsum(acc);
    if (lane == 0) denom[row] = acc;
}

__global__ void k_predict(const u16* __restrict__ tok, const float* __restrict__ pw,
                          float* __restrict__ out)
{
    int b = blockIdx.x;
    int lane = threadIdx.x;
    const u16* rp = tok + ((long)b * 2048 + 2047) * P;
    float acc = 0.f;
    for (int t = lane; t < 513; t += 64) acc += bf2f(rp[t]) * pw[t];
    acc = wredsum(acc);
    if (lane == 0) out[b] = acc;
}

// ---------------------------------------------------------------------------
// 256x256 software-pipelined QKV GEMM. M=131072, N=1664 (7 tiles), K=576.
// Per phase: [STAGE half-tile (tile kt+1) | lgkmcnt(0) | vmcnt(4) | s_barrier |
//             MFMA quadrant (frags preloaded) | ds_read frags for next phase].
// Quadrants per tile: p0:(0,0) p1:(0,1) p2:(1,1) p3:(1,0).
// Stage order per tile: p0:A0'' p1:B0'' p2:B1'' p3:A1''.
// Slot reads:  p0: bf1(B1,cur)  p1: afB(A1,cur)  p2: -  p3: afA(A0,nxt)+b0(B0,nxt).
// Landing: vmcnt(4) before bar_u => stages <= u-2 landed for ALL waves.
// B0 frags double-buffered by tile parity (b0a/b0b); 2-tile unrolled loop.
// ---------------------------------------------------------------------------
#define QN 1664

#define QSTAGE(DB, HALF, K0)                                                   \
    {                                                                          \
        _Pragma("unroll")                                                      \
        for (int j = 0; j < 2; j++) {                                          \
            int row_ = j * 64 + srow;                                          \
            const u16* src_;                                                   \
            if ((HALF) < 2) {                                                  \
                src_ = Ag + (long)(m0 + (HALF) * 128 + row_) * 576 + (K0) + colsw; \
            } else {                                                           \
                int gc_ = n0 + ((HALF) - 2) * 128 + row_;                      \
                if (gc_ >= QN) gc_ = QN - 1;                                   \
                src_ = Bg + (long)gc_ * 576 + (K0) + colsw;                    \
            }                                                                  \
            gload_lds16(src_, S + (DB) * 32768 + (HALF) * 8192 + j * 4096 + w * 512); \
        }                                                                      \
    }

#define QLGKM0 asm volatile("s_waitcnt lgkmcnt(0)" ::: "memory");
#define QVM4   asm volatile("s_waitcnt vmcnt(4)" ::: "memory");
#define QBAR   __builtin_amdgcn_s_barrier();                                   \
               __builtin_amdgcn_sched_barrier(0);

#define QMFMA(AF, BF, AH, BH)                                                  \
    __builtin_amdgcn_s_setprio(1);                                             \
    _Pragma("unroll")                                                          \
    for (int m_ = 0; m_ < 4; m_++)                                             \
        _Pragma("unroll")                                                      \
        for (int n_ = 0; n_ < 2; n_++) {                                       \
            acc[AH][BH][m_][n_] =                                              \
                mfma_16x16x32_bf16(AF[m_][0], BF[n_][0], acc[AH][BH][m_][n_]); \
            acc[AH][BH][m_][n_] =                                              \
                mfma_16x16x32_bf16(AF[m_][1], BF[n_][1], acc[AH][BH][m_][n_]); \
        }                                                                      \
    __builtin_amdgcn_s_setprio(0);

#define QLDAF(DST, BUF, AHALF)                                                 \
    _Pragma("unroll")                                                          \
    for (int m_ = 0; m_ < 4; m_++) {                                           \
        int rr_ = wr * 64 + m_ * 16 + (lane & 15);                             \
        _Pragma("unroll")                                                      \
        for (int ks_ = 0; ks_ < 2; ks_++)                                      \
            DST[m_][ks_] = *(const u16x8*)&S[(BUF) * 32768 + (AHALF) * 8192 +  \
                rr_ * 64 + ((ks_ * 32 + (lane >> 4) * 8) ^ swz)];              \
    }

#define QLDBF(DST, BUF, BHALF)                                                 \
    _Pragma("unroll")                                                          \
    for (int n_ = 0; n_ < 2; n_++) {                                           \
        int cc_ = wc * 32 + n_ * 16 + (lane & 15);                             \
        _Pragma("unroll")                                                      \
        for (int ks_ = 0; ks_ < 2; ks_++)                                      \
            DST[n_][ks_] = *(const u16x8*)&S[(BUF) * 32768 + 16384 +           \
                (BHALF) * 8192 + cc_ * 64 + ((ks_ * 32 + (lane >> 4) * 8) ^ swz)]; \
    }

// One K-tile, parity PI (buffer), B0CUR = retained B0 frags, B0NXT = other
// parity set, K1 = k0 of the tile being staged, DOLAST = load next-tile frags.
#define QTILE(PI, B0CUR, B0NXT, K1, DOLAST)                                    \
    /* p0 */ QSTAGE((PI) ^ 1, 0, K1) QLGKM0 QVM4 QBAR                          \
    QMFMA(afA, B0CUR, 0, 0)                                                    \
    QLDBF(bf1, PI, 1)                                                          \
    /* p1 */ QSTAGE((PI) ^ 1, 2, K1) QLGKM0 QVM4 QBAR                          \
    QMFMA(afA, bf1, 0, 1)                                                      \
    QLDAF(afB, PI, 1)                                                          \
    /* p2 */ QSTAGE((PI) ^ 1, 3, K1) QLGKM0 QVM4 QBAR                          \
    QMFMA(afB, bf1, 1, 1)                                                      \
    /* p3 */ QSTAGE((PI) ^ 1, 1, K1) QLGKM0 QVM4 QBAR                          \
    QMFMA(afB, B0CUR, 1, 0)                                                    \
    if (DOLAST) { QLDAF(afA, (PI) ^ 1, 0) QLDBF(B0NXT, (PI) ^ 1, 0) }

__global__ __launch_bounds__(512, 2) void k_qkv8(
    const u16* __restrict__ Ag, const u16* __restrict__ Bg, u16* __restrict__ C,
    const float* __restrict__ meanb, const float* __restrict__ rstdb,
    const float* __restrict__ s1l, const float* __restrict__ s2l,
    u16* __restrict__ VT)
{
    extern __shared__ u16 S[];
    int id = blockIdx.x;
    int lin = (id & 7) * 448 + (id >> 3);
    int mt = lin / 7, nt = lin - mt * 7;
    int m0 = mt * 256, n0 = nt * 256;
    int tid = threadIdx.x, lane = tid & 63, w = tid >> 6;
    int wr = w >> 2, wc = w & 3;

    float* auxp = (float*)(S + 65536);   // mean[256] rstd[256] s1[256] s2[256]
    if (tid < 256) {
        auxp[tid] = meanb[(long)m0 + tid];
        auxp[256 + tid] = rstdb[(long)m0 + tid];
    } else {
        int t = tid - 256;
        int gc = n0 + t; if (gc >= QN) gc = QN - 1;
        auxp[512 + t] = s1l[gc];
        auxp[768 + t] = s2l[gc];
    }

    int srow = (w << 3) + (lane >> 3);
    int colsw = ((lane & 7) << 3) ^ ((lane >> 3) << 3);
    int swz = (lane & 7) << 3;

    f32x4 acc[2][2][4][2];
#pragma unroll
    for (int a_ = 0; a_ < 2; a_++)
#pragma unroll
    for (int b_ = 0; b_ < 2; b_++)
#pragma unroll
    for (int m_ = 0; m_ < 4; m_++)
#pragma unroll
    for (int n_ = 0; n_ < 2; n_++) {
        acc[a_][b_][m_][n_][0] = 0.f; acc[a_][b_][m_][n_][1] = 0.f;
        acc[a_][b_][m_][n_][2] = 0.f; acc[a_][b_][m_][n_][3] = 0.f;
    }
    u16x8 afA[4][2], afB[4][2], bf1[2][2], b0a[2][2], b0b[2][2];

    // prologue: stage tile 0 (A0,B0,B1,A1) into buf0; A0,B0 landed; preload.
    QSTAGE(0, 0, 0) QSTAGE(0, 2, 0) QSTAGE(0, 3, 0) QSTAGE(0, 1, 0)
    QVM4
    __builtin_amdgcn_s_barrier();
    QLDAF(afA, 0, 0) QLDBF(b0a, 0, 0)

#pragma unroll 1
    for (int it = 0; it < 4; ++it) {
        int k1a = it * 128 + 64;
        int k1b = it * 128 + 128;
        QTILE(0, b0a, b0b, k1a, 1)
        QTILE(1, b0b, b0a, k1b, 1)
    }
    // tail tile 8 (parity 0); stages are redundant re-loads of k0=512.
    QTILE(0, b0a, b0b, 512, 0)

    asm volatile("s_waitcnt vmcnt(0)" ::: "memory");
    __builtin_amdgcn_s_barrier();

    // ------------------------------------------------------------- epilogue
    if (n0 < 1024) {
#pragma unroll
        for (int ah = 0; ah < 2; ah++)
#pragma unroll
        for (int bh = 0; bh < 2; bh++)
#pragma unroll
        for (int m_ = 0; m_ < 4; m_++)
#pragma unroll
        for (int n_ = 0; n_ < 2; n_++) {
            int lr0 = ah * 128 + wr * 64 + m_ * 16 + ((lane >> 4) << 2);
            int lc = bh * 128 + wc * 32 + n_ * 16 + (lane & 15);
            float s1c = auxp[512 + lc], s2c = auxp[768 + lc];
#pragma unroll
            for (int r_ = 0; r_ < 4; r_++) {
                int lr = lr0 + r_;
                float v = auxp[256 + lr] * (acc[ah][bh][m_][n_][r_]
                          - auxp[lr] * s1c) + s2c;
                S[lr * 256 + (lc ^ ((lr & 7) << 3))] = f2bf(v);
            }
        }
        __syncthreads();
#pragma unroll
        for (int i = 0; i < 16; i++) {
            int g = i * 512 + tid;
            int row = g >> 5, c0 = (g & 31) * 8;
            *(u16x8*)&C[(long)(m0 + row) * 1664 + n0 + c0] =
                *(const u16x8*)&S[row * 256 + (c0 ^ ((row & 7) << 3))];
        }
    } else {
        int u0 = n0 - 1024, b = m0 >> 11, nloc = m0 & 2047;
#pragma unroll
        for (int ah = 0; ah < 2; ah++)
#pragma unroll
        for (int bh = 0; bh < 2; bh++)
#pragma unroll
        for (int m_ = 0; m_ < 4; m_++)
#pragma unroll
        for (int n_ = 0; n_ < 2; n_++) {
            int lr0 = ah * 128 + wr * 64 + m_ * 16 + ((lane >> 4) << 2);
            int lc = bh * 128 + wc * 32 + n_ * 16 + (lane & 15);
            float s1c = auxp[512 + lc], s2c = auxp[768 + lc];
#pragma unroll
            for (int r_ = 0; r_ < 4; r_++) {
                int lr = lr0 + r_;
                float v = auxp[256 + lr] * (acc[ah][bh][m_][n_][r_]
                          - auxp[lr] * s1c) + s2c;
                S[lc * 256 + (lr ^ ((lc & 7) << 3))] = f2bf(v);
            }
        }
        __syncthreads();
        const u16x8 ones = {0x3F80,0x3F80,0x3F80,0x3F80,0x3F80,0x3F80,0x3F80,0x3F80};
#pragma unroll
        for (int i = 0; i < 16; i++) {
            int g = i * 512 + tid;
            int ur = g >> 5, t0 = (g & 31) * 8;
            int u = u0 + ur;
            if (u < VTROWS) {
                u16x8 vv;
                if (u == 513) vv = ones;
                else vv = *(const u16x8*)&S[ur * 256 + (t0 ^ ((ur & 7) << 3))];
                *(u16x8*)&VT[((long)b * VTROWS + u) * 2048 + nloc + t0] = vv;
            }
        }
    }
}

// ---------------------------------------------------------------------------
// GEMM C[m][n] = sum_{k<K} A[m][k]*Bt[n][k]  (+ A[m][K]*Bt[n][K] if r1).
// 128x128 tile, BK=64, 4 waves. 1-D grid, bijective XCD-chunked swizzle.
// T2 LDS XOR-swizzle (both-sides): pre-swizzled global source column for
// global_load_lds + matching XOR on ds_read_b128 fragment reads.
__global__ __launch_bounds__(256) void k_gemm_bt(
    const u16* __restrict__ A, const u16* __restrict__ Bt, u16* __restrict__ C,
    int M, int N, int K, int lda, int ldb, int ldc,
    long sA, long sB, long sC,
    const float* __restrict__ aux1, const float* __restrict__ aux2,
    const float* __restrict__ aux3, const float* __restrict__ aux4,
    long sAux, const u16* __restrict__ Res,
    float cscale, int mode, int r1, int padw,
    int ntm, int ntn, int nbz,
    u16* __restrict__ VT, int vtbase)
{
    int G = ntm * ntn * nbz;
    int id = blockIdx.x;
    int lin = (id & 7) * (G >> 3) + (id >> 3);
    int per = ntm * ntn;
    int bz = lin / per;
    int rem = lin - bz * per;
    int mt = rem / ntn;
    int nt = rem - mt * ntn;
    int m0 = mt * 128, n0 = nt * 128;

    A += (long)bz * sA; Bt += (long)bz * sB; C += (long)bz * sC;
    int tid = threadIdx.x, lane = tid & 63, w = tid >> 6;
    int wr = w >> 1, wc = w & 1;
    __shared__ u16 ldsbuf[2 * 128 * 64];      // Als | Bls; then Res/C tile
    u16* Als = ldsbuf;
    u16* Bls = ldsbuf + 128 * 64;
    __shared__ float auxR0[128], auxR1[128], auxA1[128];
    __shared__ float auxC0[128], auxC1[128], auxB1[128];

    if (tid < 128) {
        int gr = m0 + tid; if (gr >= M) gr = M - 1;
        float r0v = cscale, r1v = 0.f, a1v = 0.f;
        if (mode == 1) {
            const float* d1 = aux1 + (long)bz * sAux;
            r0v = cscale / (d1[gr] + 1e-6f);
        } else if (mode == 3) { r0v = aux1[gr]; r1v = aux2[gr]; }
        if (r1) a1v = bf2f(A[(long)gr * lda + K]);
        auxR0[tid] = r0v; auxR1[tid] = r1v; auxA1[tid] = a1v;
    } else {
        int t = tid - 128;
        int gc = n0 + t; if (gc >= N) gc = N - 1;
        float c0v = 0.f, c1v = 0.f, b1v = 0.f;
        if (mode == 3) { c0v = aux3[gc]; c1v = aux4[gc]; }
        if (r1) b1v = bf2f(Bt[(long)gc * ldb + K]);
        auxC0[t] = c0v; auxC1[t] = c1v; auxB1[t] = b1v;
    }

    f32x4 acc[4][4];
#pragma unroll
    for (int m = 0; m < 4; m++)
#pragma unroll
        for (int n = 0; n < 4; n++) { acc[m][n][0]=0.f; acc[m][n][1]=0.f; acc[m][n][2]=0.f; acc[m][n][3]=0.f; }

    int srow = lane >> 3;
    int scol = (lane & 7) * 8;
    int scolsw = scol ^ (srow << 3);
    int swz = (lane & 7) << 3;

    for (int k0 = 0; k0 < K; k0 += 64) {
#pragma unroll
        for (int i = 0; i < 4; i++) {
            int rt = (w * 4 + i) * 8 + srow;
            int gr = m0 + rt; gr = (gr < M) ? gr : (M - 1);
            gload_lds16(A + (long)gr * lda + k0 + scolsw, &Als[(w * 4 + i) * 512]);
        }
#pragma unroll
        for (int i = 0; i < 4; i++) {
            int rt = (w * 4 + i) * 8 + srow;
            int gc = n0 + rt; gc = (gc < N) ? gc : (N - 1);
            gload_lds16(Bt + (long)gc * ldb + k0 + scolsw, &Bls[(w * 4 + i) * 512]);
        }
        __syncthreads();
#pragma unroll
        for (int ks = 0; ks < 2; ks++) {
            u16x8 af[4], bfv[4];
#pragma unroll
            for (int m = 0; m < 4; m++) {
                int row = wr * 64 + m * 16 + (lane & 15);
                af[m] = *(const u16x8*)&Als[row * 64 + ((ks * 32 + (lane >> 4) * 8) ^ swz)];
            }
#pragma unroll
            for (int n = 0; n < 4; n++) {
                int col = wc * 64 + n * 16 + (lane & 15);
                bfv[n] = *(const u16x8*)&Bls[col * 64 + ((ks * 32 + (lane >> 4) * 8) ^ swz)];
            }
#pragma unroll
            for (int m = 0; m < 4; m++)
#pragma unroll
                for (int n = 0; n < 4; n++)
                    acc[m][n] = mfma_16x16x32_bf16(af[m], bfv[n], acc[m][n]);
        }
        __syncthreads();
    }
    // LDS (Als/Bls) now dead; reuse for Res/C tile.

    bool isvt = (VT != nullptr) && (n0 >= vtbase);

    if (Res) {
        const u16* Rp = Res + (long)bz * sC;
#pragma unroll
        for (int i = 0; i < 8; i++) {
            int lrow = i * 16 + (tid >> 4);
            int lcol = (tid & 15) * 8;
            long gr = m0 + lrow; if (gr > (long)M - 1) gr = M - 1;
            long gcol = (long)n0 + lcol;
            long mx = (long)ldc - 8; if (gcol > mx) gcol = mx;
            *(u16x8*)&ldsbuf[lrow * 128 + lcol] = *(const u16x8*)&Rp[gr * ldc + gcol];
        }
        __syncthreads();
    }

    asm volatile("s_nop 7\n\ts_nop 7" ::: );

    if (!isvt) {
        // normal pack: ldsbuf[row][col]
#pragma unroll
        for (int m = 0; m < 4; m++) {
            int lrbase = wr * 64 + m * 16 + ((lane >> 4) << 2);
#pragma unroll
            for (int n = 0; n < 4; n++) {
                int lc = wc * 64 + n * 16 + (lane & 15);
                float c0v = auxC0[lc], c1v = auxC1[lc], b1v = auxB1[lc];
#pragma unroll
                for (int r = 0; r < 4; r++) {
                    int lr = lrbase + r;
                    float wv = acc[m][n][r] + auxA1[lr] * b1v;
                    float v;
                    if (mode == 3) v = auxR1[lr] * (wv - auxR0[lr] * c0v) + c1v;
                    else {
                        v = wv * auxR0[lr];
                        if (Res) v += bf2f(ldsbuf[lr * 128 + lc]);
                    }
                    ldsbuf[lr * 128 + lc] = f2bf(v);
                }
            }
        }
        __syncthreads();

        int lcol = (tid & 15) * 8;
        int gc0 = n0 + lcol;
        bool colok = padw || (gc0 + 8 <= N);
#pragma unroll
        for (int i = 0; i < 8; i++) {
            int lrow = i * 16 + (tid >> 4);
            int gr = m0 + lrow;
            if (gr < M && colok) {
                *(u16x8*)&C[(long)gr * ldc + gc0] = *(const u16x8*)&ldsbuf[lrow * 128 + lcol];
            }
        }
    } else {
        // V-direct: pack transposed + XOR-swizzled: ldsbuf[u][token^((u&7)<<3)]
        int u0 = n0 - vtbase;
        int b = m0 >> 11;
        int nloc = m0 & 2047;
#pragma unroll
        for (int m = 0; m < 4; m++) {
            int lrbase = wr * 64 + m * 16 + ((lane >> 4) << 2);
#pragma unroll
            for (int n = 0; n < 4; n++) {
                int lc = wc * 64 + n * 16 + (lane & 15);
                float c0v = auxC0[lc], c1v = auxC1[lc];
#pragma unroll
                for (int r = 0; r < 4; r++) {
                    int lr = lrbase + r;
                    float wv = acc[m][n][r];
                    float v = (mode == 3) ? (auxR1[lr] * (wv - auxR0[lr] * c0v) + c1v)
                                          : (wv * auxR0[lr]);
                    ldsbuf[lc * 128 + (lr ^ ((lc & 7) << 3))] = f2bf(v);
                }
            }
        }
        __syncthreads();

        int nc = (tid & 15) * 8;          // token offset, 8-contiguous
        const u16x8 ones = {0x3F80,0x3F80,0x3F80,0x3F80,0x3F80,0x3F80,0x3F80,0x3F80};
#pragma unroll
        for (int i = 0; i < 8; i++) {
            int ur = i * 16 + (tid >> 4);
            int u = u0 + ur;
            if (u < VTROWS) {
                u16x8 vv;
                if (u == 513) vv = ones;
                else vv = *(const u16x8*)&ldsbuf[ur * 128 + (nc ^ ((ur & 7) << 3))];
                *(u16x8*)&VT[((long)b * VTROWS + u) * 2048 + nloc + nc] = vv;
            }
        }
    }
}

// ---------------------------------------------------------------------------
extern "C" void kernel_launch(void* const* d_in, const int* in_sizes, int n_in,
                              void* d_out, int out_size, void* d_ws, size_t ws_size,
                              hipStream_t stream)
{
    const float* xs    = (const float*)d_in[0];
    const float* ys    = (const float*)d_in[1];
    const float* qx    = (const float*)d_in[2];
    const float* Wq    = (const float*)d_in[3];
    const float* Wk    = (const float*)d_in[4];
    const float* Wv    = (const float*)d_in[5];
    const float* Wo    = (const float*)d_in[6];
    const float* ln1w  = (const float*)d_in[7];
    const float* ln1b  = (const float*)d_in[8];
    const float* ln2w  = (const float*)d_in[9];
    const float* ln2b  = (const float*)d_in[10];
    const float* scale = (const float*)d_in[11];
    const float* predw = (const float*)d_in[12];
    float* out = (float*)d_out;

    char* ws = (char*)d_ws;
    u16*   tok   = (u16*)(ws + 0L);              // 150,994,944
    u16*   buf1  = (u16*)(ws + 150994944L);      // 150,994,944  vt then z
    u16*   qkv   = (u16*)(ws + 301989888L);      // 436,207,616
    u16*   kpt   = (u16*)(ws + 738197504L);      // 134,217,728  Kp^T / w2t
    u16*   kvh   = (u16*)(ws + 872415232L);      //  41,943,040
    float* denom = (float*)(ws + 914358272L);
    float* meanb = (float*)(ws + 914882560L);
    float* rstdb = (float*)(ws + 915406848L);
    float* ksum  = (float*)(ws + 915931136L);
    u16*   wcat  = (u16*)(ws + 916062208L);
    u16*   wop   = (u16*)(ws + 923729920L);
    float* s1    = (float*)(ws + 926384128L);
    float* s2    = (float*)(ws + 926410752L);
    float* rkb   = (float*)(ws + 301465600L);    // tail of buf1 region
    u16*   w2t   = kpt;

    static bool attr_done = false;
    if (!attr_done) {
        (void)hipFuncSetAttribute((const void*)k_qkv8,
            hipFuncAttributeMaxDynamicSharedMemorySize, 135168);
        attr_done = true;
    }

    k_build_tokens<<<32768, 256, 0, stream>>>(xs, ys, qx, tok, meanb, rstdb);
    {
        long n1 = 4L * NQK * P;
        k_prep_wcat<<<(int)((n1 + 255) / 256), 256, 0, stream>>>(Wq, Wk, Wv, ln1w, wcat);
        long n2 = 4L * P * P;
        k_prep_wo<<<(int)((n2 + 255) / 256), 256, 0, stream>>>(Wo, wop);
        k_prep_sums<<<1664, 256, 0, stream>>>(Wq, Wk, Wv, ln1w, ln1b, s1, s2);
    }

    for (int l = 0; l < 4; l++) {
        // QKV = LN-folded GEMM (K=576); 256x256 pipelined; V tiles -> vt
        k_qkv8<<<3584, 512, 135168, stream>>>(tok, wcat + (long)l * NQK * P, qkv,
            meanb, rstdb, s1 + l * NQK, s2 + l * NQK, buf1);
        // Qp in place + rk
        k_qknorm<<<32768, 256, 0, stream>>>(qkv, rkb, scale, l);
        // Kp^T tiles only
        {
            dim3 g(8, 2048, 1);
            k_trans<<<g, 256, 0, stream>>>(qkv, rkb, kpt);
        }
        // kvh[b][h][u] = sum_n Kp[n][h] V[n][u]  (col 513 = Ksum)
        k_gemm_bt<<<1280, 256, 0, stream>>>(kpt, buf1, kvh,
            512, VTROWS, 2048, 2048, 2048, KVLD,
            512L * 2048, (long)VTROWS * 2048, 512L * KVLD,
            nullptr, nullptr, nullptr, nullptr, 0, nullptr, 1.f, 0, 0, 1,
            4, 5, 64, nullptr, 1 << 30);
        k_extract_ksum<<<64, 512, 0, stream>>>(kvh, ksum);
        k_denom<<<32768, 256, 0, stream>>>(qkv, ksum, denom);
        // w2t[b][t][h] = sum_{u<=512} Wo[t][u] kvh[b][h][u]  (K=512 + rank-1)
        k_gemm_bt<<<1280, 256, 0, stream>>>(wop + (long)l * P * P, kvh, w2t,
            576, 512, 512, P, KVLD, 512,
            0, 512L * KVLD, 576L * 512,
            nullptr, nullptr, nullptr, nullptr, 0, nullptr, 1.f, 0, 1, 0,
            5, 4, 64, nullptr, 1 << 30);
        // z = 0.1*(Qp @ w2t^T)/(denom+eps) + tok
        k_gemm_bt<<<5120, 256, 0, stream>>>(qkv, w2t, buf1,
            2048, P, 512, NQK, 512, P,
            2048L * NQK, 576L * 512, 2048L * P,
            denom, nullptr, nullptr, nullptr, 2048, tok,
            0.1f, 1, 0, 0, 16, 5, 64, nullptr, 1 << 30);
        // tok = LN2(z) + next-layer stats
        k_ln2<<<32768, 256, 0, stream>>>(buf1, tok, ln2w + l * 513, ln2b + l * 513,
                                         meanb, rstdb);
    }
    k_predict<<<64, 64, 0, stream>>>(tok, predw, out);
}

// Round 4
// 3599.097 us; speedup vs baseline: 1.0002x; 1.0002x over previous
//
#include <hip/hip_runtime.h>
#include <cstdint>
#include <cstddef>

// ---------------------------------------------------------------------------
// MultiLayerAttentionModel on MI355X (gfx950), bf16 MFMA pipeline, round 11.
// Round 10 with ONE change: k_qkv8 __launch_bounds__(512,2) -> (512,1).
// R10's VGPR cap (128) caused scratch spills (+74MB fetch, +86MB write,
// VGPR_Count==128 exactly); LDS (132KB) limits to 1 block/CU anyway, so the
// cap bought nothing. Releasing it lets the pipelined schedule run spill-free.
// ---------------------------------------------------------------------------

typedef unsigned short u16;
typedef float f32x4 __attribute__((ext_vector_type(4)));
typedef unsigned short u16x8 __attribute__((ext_vector_type(8)));

#define P 576
#define NQK 1664
#define VTROWS 514
#define KVLD 640

__device__ __forceinline__ float bf2f(u16 s) {
    union { unsigned u; float f; } v; v.u = ((unsigned)s) << 16; return v.f;
}
__device__ __forceinline__ u16 f2bf(float f) {
    union { float f; unsigned u; } v; v.f = f;
    unsigned r = v.u + 0x7FFF + ((v.u >> 16) & 1);
    return (u16)(r >> 16);
}
__device__ __forceinline__ float wredsum(float v) {
#pragma unroll
    for (int o = 32; o > 0; o >>= 1) v += __shfl_xor(v, o, 64);
    return v;
}
__device__ __forceinline__ f32x4 mfma_16x16x32_bf16(u16x8 a, u16x8 b, f32x4 c) {
    asm volatile("v_mfma_f32_16x16x32_bf16 %0, %1, %2, %0"
                 : "+v"(c) : "v"(a), "v"(b));
    return c;
}
__device__ __forceinline__ void gload_lds16(const u16* g, u16* l) {
    __builtin_amdgcn_global_load_lds(
        (const __attribute__((address_space(1))) void*)g,
        (__attribute__((address_space(3))) void*)l, 16, 0, 0);
}

// ---------------------------------------------------------------------------
__global__ __launch_bounds__(256) void k_build_tokens(
    const float* __restrict__ xs, const float* __restrict__ ys,
    const float* __restrict__ qx, u16* __restrict__ tok,
    float* __restrict__ meanb, float* __restrict__ rstdb)
{
    long row = (long)blockIdx.x * 4 + (threadIdx.x >> 6);
    int lane = threadIdx.x & 63;
    int b = (int)(row >> 11), n = (int)(row & 2047);
    const float* src = (n < 2047) ? xs + ((long)(b * 2047 + n)) * 512
                                  : qx + (long)b * 512;
    float4 f0 = *(const float4*)(src + lane * 8);
    float4 f1 = *(const float4*)(src + lane * 8 + 4);
    float y = (n < 2047) ? ys[(long)b * 2047 + n] : 0.f;
    float v[8] = {f0.x, f0.y, f0.z, f0.w, f1.x, f1.y, f1.z, f1.w};
    float s = 0.f, sq = 0.f;
#pragma unroll
    for (int j = 0; j < 8; j++) { s += v[j]; sq += v[j] * v[j]; }
    if (lane == 0) { s += y; sq += y * y; }
    s = wredsum(s); sq = wredsum(sq);
    u16x8 o;
#pragma unroll
    for (int j = 0; j < 8; j++) o[j] = f2bf(v[j]);
    *(u16x8*)(tok + row * P + lane * 8) = o;
    if (lane < 8) {
        u16x8 z8 = {0,0,0,0,0,0,0,0};
        if (lane == 0) z8[0] = f2bf(y);
        *(u16x8*)(tok + row * P + 512 + lane * 8) = z8;
    }
    if (lane == 0) {
        float m = s * (1.f / 513.f);
        float var = sq * (1.f / 513.f) - m * m;
        meanb[row] = m;
        rstdb[row] = 1.f / sqrtf(var + 1e-5f);
    }
}

__global__ __launch_bounds__(256) void k_prep_wcat(
    const float* __restrict__ wq, const float* __restrict__ wk,
    const float* __restrict__ wv, const float* __restrict__ ln1w,
    u16* __restrict__ wcat)
{
    long idx = (long)blockIdx.x * 256 + threadIdx.x;
    if (idx >= 4L * NQK * P) return;
    int t = (int)(idx % P);
    long rem = idx / P;
    int r = (int)(rem % NQK);
    int l = (int)(rem / NQK);
    float v = 0.f;
    if (t < 513) {
        float wsc = ln1w[l * 513 + t];
        if (r < 512)       v = wq[((long)l * 512 + r) * 513 + t] * wsc;
        else if (r < 1024) v = wk[((long)l * 512 + (r - 512)) * 513 + t] * wsc;
        else if (r < 1537) v = wv[((long)l * 513 + (r - 1024)) * 513 + t] * wsc;
    }
    wcat[idx] = f2bf(v);
}

__global__ __launch_bounds__(256) void k_prep_wo(
    const float* __restrict__ wo, u16* __restrict__ wop)
{
    long idx = (long)blockIdx.x * 256 + threadIdx.x;
    if (idx >= 4L * P * P) return;
    int u = (int)(idx % P);
    long rem = idx / P;
    int t = (int)(rem % P);
    int l = (int)(rem / P);
    float v = (t < 513 && u < 513) ? wo[((long)l * 513 + t) * 513 + u] : 0.f;
    wop[idx] = f2bf(v);
}

__global__ __launch_bounds__(256) void k_prep_sums(
    const float* __restrict__ wq, const float* __restrict__ wk,
    const float* __restrict__ wv, const float* __restrict__ ln1w,
    const float* __restrict__ ln1b, float* __restrict__ s1, float* __restrict__ s2)
{
    int id = blockIdx.x * 4 + (threadIdx.x >> 6);
    int lane = threadIdx.x & 63;
    int l = id / NQK, r = id % NQK;
    float a1 = 0.f, a2 = 0.f;
    for (int t = lane; t < 513; t += 64) {
        float wc = 0.f;
        if (r < 512)       wc = wq[((long)l * 512 + r) * 513 + t];
        else if (r < 1024) wc = wk[((long)l * 512 + (r - 512)) * 513 + t];
        else if (r < 1537) wc = wv[((long)l * 513 + (r - 1024)) * 513 + t];
        a1 += ln1w[l * 513 + t] * wc;
        a2 += ln1b[l * 513 + t] * wc;
    }
    a1 = wredsum(a1); a2 = wredsum(a2);
    if (lane == 0) { s1[id] = a1; s2[id] = a2; }
}

// ---------------------------------------------------------------------------
__global__ __launch_bounds__(256) void k_ln2(
    const u16* __restrict__ z, u16* __restrict__ tok,
    const float* __restrict__ w, const float* __restrict__ bia,
    float* __restrict__ meanb, float* __restrict__ rstdb)
{
    long row = (long)blockIdx.x * 4 + (threadIdx.x >> 6);
    int lane = threadIdx.x & 63;
    const u16* zp = z + row * P;
    u16* tp = tok + row * P;
    u16x8 a0 = *(const u16x8*)(zp + lane * 8);
    u16x8 a1 = {0,0,0,0,0,0,0,0};
    if (lane < 8) a1 = *(const u16x8*)(zp + 512 + lane * 8);
    float v0[8], v1[8];
#pragma unroll
    for (int j = 0; j < 8; j++) v0[j] = bf2f(a0[j]);
#pragma unroll
    for (int j = 0; j < 8; j++) v1[j] = (lane < 8) ? bf2f(a1[j]) : 0.f;
    float s = 0.f, sq = 0.f;
#pragma unroll
    for (int j = 0; j < 8; j++) { s += v0[j]; sq += v0[j] * v0[j]; }
#pragma unroll
    for (int j = 0; j < 8; j++) { s += v1[j]; sq += v1[j] * v1[j]; }
    s = wredsum(s); sq = wredsum(sq);
    float mean = s * (1.f / 513.f);
    float var = sq * (1.f / 513.f) - mean * mean;
    float rstd = 1.f / sqrtf(var + 1e-5f);
    float so = 0.f, so2 = 0.f;
    u16x8 o0;
    float of0[8];
#pragma unroll
    for (int j = 0; j < 8; j++) {
        int t = lane * 8 + j;
        of0[j] = (v0[j] - mean) * rstd * w[t] + bia[t];
        so += of0[j]; so2 += of0[j] * of0[j];
        o0[j] = f2bf(of0[j]);
    }
    float of1[8];
#pragma unroll
    for (int j = 0; j < 8; j++) {
        int t = 512 + lane * 8 + j;
        float ov = 0.f;
        if (lane < 8 && t < 513) ov = (v1[j] - mean) * rstd * w[t] + bia[t];
        of1[j] = ov;
        so += ov; so2 += ov * ov;
    }
    so = wredsum(so); so2 = wredsum(so2);
    *(u16x8*)(tp + lane * 8) = o0;
    if (lane < 8) {
        u16x8 o1;
#pragma unroll
        for (int j = 0; j < 8; j++) o1[j] = f2bf(of1[j]);
        *(u16x8*)(tp + 512 + lane * 8) = o1;
    }
    if (lane == 0) {
        float m2 = so * (1.f / 513.f);
        float v2 = so2 * (1.f / 513.f) - m2 * m2;
        meanb[row] = m2;
        rstdb[row] = 1.f / sqrtf(v2 + 1e-5f);
    }
}

// ---------------------------------------------------------------------------
__global__ __launch_bounds__(256) void k_qknorm(
    u16* __restrict__ qkv, float* __restrict__ rkout,
    const float* __restrict__ scale, int l)
{
    long row = (long)blockIdx.x * 4 + (threadIdx.x >> 6);
    int lane = threadIdx.x & 63;
    float s = log1pf(expf(scale[l]));
    u16* rowp = qkv + row * NQK;
    u16x8 q8 = *(const u16x8*)(rowp + lane * 8);
    u16x8 k8 = *(const u16x8*)(rowp + 512 + lane * 8);
    float qf[8];
    float sqv = 0.f, skv = 0.f;
#pragma unroll
    for (int j = 0; j < 8; j++) { qf[j] = bf2f(q8[j]); sqv += qf[j] * qf[j]; }
#pragma unroll
    for (int j = 0; j < 8; j++) { float kf = bf2f(k8[j]); skv += kf * kf; }
    sqv = wredsum(sqv); skv = wredsum(skv);
    float rnq = 1.f / fmaxf(sqrtf(sqv), 1e-12f);
    float rnk = 1.f / fmaxf(sqrtf(skv), 1e-12f);
    u16x8 o;
#pragma unroll
    for (int j = 0; j < 8; j++) {
        float q = qf[j] * rnq;
        float qp = (q > 0.f) ? (q + 1.f) : expf(q);
        o[j] = f2bf(qp * s);
    }
    *(u16x8*)(rowp + lane * 8) = o;
    if (lane == 0) rkout[row] = rnk;
}

// ---------------------------------------------------------------------------
// K-section transpose only: ct in 0..7 -> kpt[b][h][n] with elu(K*rk)+1.
__global__ __launch_bounds__(256) void k_trans(
    const u16* __restrict__ qkv, const float* __restrict__ rk,
    u16* __restrict__ kpt)
{
    int ct = blockIdx.x;
    long r0 = (long)blockIdx.y * 64;
    int b = (int)(r0 >> 11);
    int nloc = (int)(r0 & 2047);
    int tid = threadIdx.x;
    int r = tid >> 2;
    int c0 = (tid & 3) * 16;
    __shared__ u16 T[64 * 80];
    const u16* src = qkv + (r0 + r) * NQK + 512 + ct * 64 + c0;
    u16x8 a = *(const u16x8*)src;
    u16x8 d = *(const u16x8*)(src + 8);
    float rkv = rk[r0 + r];
#pragma unroll
    for (int j = 0; j < 8; j++) {
        float kv = bf2f(a[j]) * rkv; kv = (kv > 0.f) ? kv + 1.f : expf(kv);
        T[(c0 + j) * 80 + r] = f2bf(kv);
    }
#pragma unroll
    for (int j = 0; j < 8; j++) {
        float kv = bf2f(d[j]) * rkv; kv = (kv > 0.f) ? kv + 1.f : expf(kv);
        T[(c0 + 8 + j) * 80 + r] = f2bf(kv);
    }
    __syncthreads();
    int orow = tid >> 2;
    int oc0 = (tid & 3) * 16;
    u16x8 w0 = *(const u16x8*)&T[orow * 80 + oc0];
    u16x8 w1 = *(const u16x8*)&T[orow * 80 + oc0 + 8];
    u16* dst = kpt + ((long)b * 512 + ct * 64 + orow) * 2048 + nloc + oc0;
    *(u16x8*)dst = w0;
    *(u16x8*)(dst + 8) = w1;
}

// ---------------------------------------------------------------------------
__global__ __launch_bounds__(512) void k_extract_ksum(
    const u16* __restrict__ kvh, float* __restrict__ ksum)
{
    int b = blockIdx.x, h = threadIdx.x;
    ksum[(long)b * 512 + h] = bf2f(kvh[((long)b * 512 + h) * KVLD + 513]);
}

__global__ __launch_bounds__(256) void k_denom(
    const u16* __restrict__ qkv, const float* __restrict__ ksum,
    float* __restrict__ denom)
{
    long row = (long)blockIdx.x * 4 + (threadIdx.x >> 6);
    int lane = threadIdx.x & 63;
    int b = (int)(row >> 11);
    u16x8 q = *(const u16x8*)(qkv + row * NQK + lane * 8);
    const float* ks = ksum + (long)b * 512 + lane * 8;
    float acc = 0.f;
#pragma unroll
    for (int j = 0; j < 8; j++) acc += bf2f(q[j]) * ks[j];
    acc = wredsum(acc);
    if (lane == 0) denom[row] = acc;
}

__global__ void k_predict(const u16* __restrict__ tok, const float* __restrict__ pw,
                          float* __restrict__ out)
{
    int b = blockIdx.x;
    int lane = threadIdx.x;
    const u16* rp = tok + ((long)b * 2048 + 2047) * P;
    float acc = 0.f;
    for (int t = lane; t < 513; t += 64) acc += bf2f(rp[t]) * pw[t];
    acc = wredsum(acc);
    if (lane == 0) out[b] = acc;
}

// ---------------------------------------------------------------------------
// 256x256 software-pipelined QKV GEMM. M=131072, N=1664 (7 tiles), K=576.
// Per phase: [STAGE half-tile (tile kt+1) | lgkmcnt(0) | vmcnt(4) | s_barrier |
//             MFMA quadrant (frags preloaded) | ds_read frags for next phase].
// Quadrants per tile: p0:(0,0) p1:(0,1) p2:(1,1) p3:(1,0).
// Stage order per tile: p0:A0'' p1:B0'' p2:B1'' p3:A1''.
// Slot reads:  p0: bf1(B1,cur)  p1: afB(A1,cur)  p2: -  p3: afA(A0,nxt)+b0(B0,nxt).
// Landing (op-granular): vmcnt(4)=2 half-tiles in flight; stage at phase u
// lands by phase u+2; every slot-read has >=2-phase gap.
// B0 frags double-buffered by tile parity (b0a/b0b); 2-tile unrolled loop.
// ---------------------------------------------------------------------------
#define QN 1664

#define QSTAGE(DB, HALF, K0)                                                   \
    {                                                                          \
        _Pragma("unroll")                                                      \
        for (int j = 0; j < 2; j++) {                                          \
            int row_ = j * 64 + srow;                                          \
            const u16* src_;                                                   \
            if ((HALF) < 2) {                                                  \
                src_ = Ag + (long)(m0 + (HALF) * 128 + row_) * 576 + (K0) + colsw; \
            } else {                                                           \
                int gc_ = n0 + ((HALF) - 2) * 128 + row_;                      \
                if (gc_ >= QN) gc_ = QN - 1;                                   \
                src_ = Bg + (long)gc_ * 576 + (K0) + colsw;                    \
            }                                                                  \
            gload_lds16(src_, S + (DB) * 32768 + (HALF) * 8192 + j * 4096 + w * 512); \
        }                                                                      \
    }

#define QLGKM0 asm volatile("s_waitcnt lgkmcnt(0)" ::: "memory");
#define QVM4   asm volatile("s_waitcnt vmcnt(4)" ::: "memory");
#define QBAR   __builtin_amdgcn_s_barrier();                                   \
               __builtin_amdgcn_sched_barrier(0);

#define QMFMA(AF, BF, AH, BH)                                                  \
    __builtin_amdgcn_s_setprio(1);                                             \
    _Pragma("unroll")                                                          \
    for (int m_ = 0; m_ < 4; m_++)                                             \
        _Pragma("unroll")                                                      \
        for (int n_ = 0; n_ < 2; n_++) {                                       \
            acc[AH][BH][m_][n_] =                                              \
                mfma_16x16x32_bf16(AF[m_][0], BF[n_][0], acc[AH][BH][m_][n_]); \
            acc[AH][BH][m_][n_] =                                              \
                mfma_16x16x32_bf16(AF[m_][1], BF[n_][1], acc[AH][BH][m_][n_]); \
        }                                                                      \
    __builtin_amdgcn_s_setprio(0);

#define QLDAF(DST, BUF, AHALF)                                                 \
    _Pragma("unroll")                                                          \
    for (int m_ = 0; m_ < 4; m_++) {                                           \
        int rr_ = wr * 64 + m_ * 16 + (lane & 15);                             \
        _Pragma("unroll")                                                      \
        for (int ks_ = 0; ks_ < 2; ks_++)                                      \
            DST[m_][ks_] = *(const u16x8*)&S[(BUF) * 32768 + (AHALF) * 8192 +  \
                rr_ * 64 + ((ks_ * 32 + (lane >> 4) * 8) ^ swz)];              \
    }

#define QLDBF(DST, BUF, BHALF)                                                 \
    _Pragma("unroll")                                                          \
    for (int n_ = 0; n_ < 2; n_++) {                                           \
        int cc_ = wc * 32 + n_ * 16 + (lane & 15);                             \
        _Pragma("unroll")                                                      \
        for (int ks_ = 0; ks_ < 2; ks_++)                                      \
            DST[n_][ks_] = *(const u16x8*)&S[(BUF) * 32768 + 16384 +           \
                (BHALF) * 8192 + cc_ * 64 + ((ks_ * 32 + (lane >> 4) * 8) ^ swz)]; \
    }

// One K-tile, parity PI (buffer), B0CUR = retained B0 frags, B0NXT = other
// parity set, K1 = k0 of the tile being staged, DOLAST = load next-tile frags.
#define QTILE(PI, B0CUR, B0NXT, K1, DOLAST)                                    \
    /* p0 */ QSTAGE((PI) ^ 1, 0, K1) QLGKM0 QVM4 QBAR                          \
    QMFMA(afA, B0CUR, 0, 0)                                                    \
    QLDBF(bf1, PI, 1)                                                          \
    /* p1 */ QSTAGE((PI) ^ 1, 2, K1) QLGKM0 QVM4 QBAR                          \
    QMFMA(afA, bf1, 0, 1)                                                      \
    QLDAF(afB, PI, 1)                                                          \
    /* p2 */ QSTAGE((PI) ^ 1, 3, K1) QLGKM0 QVM4 QBAR                          \
    QMFMA(afB, bf1, 1, 1)                                                      \
    /* p3 */ QSTAGE((PI) ^ 1, 1, K1) QLGKM0 QVM4 QBAR                          \
    QMFMA(afB, B0CUR, 1, 0)                                                    \
    if (DOLAST) { QLDAF(afA, (PI) ^ 1, 0) QLDBF(B0NXT, (PI) ^ 1, 0) }

__global__ __launch_bounds__(512, 1) void k_qkv8(
    const u16* __restrict__ Ag, const u16* __restrict__ Bg, u16* __restrict__ C,
    const float* __restrict__ meanb, const float* __restrict__ rstdb,
    const float* __restrict__ s1l, const float* __restrict__ s2l,
    u16* __restrict__ VT)
{
    extern __shared__ u16 S[];
    int id = blockIdx.x;
    int lin = (id & 7) * 448 + (id >> 3);
    int mt = lin / 7, nt = lin - mt * 7;
    int m0 = mt * 256, n0 = nt * 256;
    int tid = threadIdx.x, lane = tid & 63, w = tid >> 6;
    int wr = w >> 2, wc = w & 3;

    float* auxp = (float*)(S + 65536);   // mean[256] rstd[256] s1[256] s2[256]
    if (tid < 256) {
        auxp[tid] = meanb[(long)m0 + tid];
        auxp[256 + tid] = rstdb[(long)m0 + tid];
    } else {
        int t = tid - 256;
        int gc = n0 + t; if (gc >= QN) gc = QN - 1;
        auxp[512 + t] = s1l[gc];
        auxp[768 + t] = s2l[gc];
    }

    int srow = (w << 3) + (lane >> 3);
    int colsw = ((lane & 7) << 3) ^ ((lane >> 3) << 3);
    int swz = (lane & 7) << 3;

    f32x4 acc[2][2][4][2];
#pragma unroll
    for (int a_ = 0; a_ < 2; a_++)
#pragma unroll
    for (int b_ = 0; b_ < 2; b_++)
#pragma unroll
    for (int m_ = 0; m_ < 4; m_++)
#pragma unroll
    for (int n_ = 0; n_ < 2; n_++) {
        acc[a_][b_][m_][n_][0] = 0.f; acc[a_][b_][m_][n_][1] = 0.f;
        acc[a_][b_][m_][n_][2] = 0.f; acc[a_][b_][m_][n_][3] = 0.f;
    }
    u16x8 afA[4][2], afB[4][2], bf1[2][2], b0a[2][2], b0b[2][2];

    // prologue: stage tile 0 (A0,B0,B1,A1) into buf0; A0,B0 landed; preload.
    QSTAGE(0, 0, 0) QSTAGE(0, 2, 0) QSTAGE(0, 3, 0) QSTAGE(0, 1, 0)
    QVM4
    __builtin_amdgcn_s_barrier();
    QLDAF(afA, 0, 0) QLDBF(b0a, 0, 0)

#pragma unroll 1
    for (int it = 0; it < 4; ++it) {
        int k1a = it * 128 + 64;
        int k1b = it * 128 + 128;
        QTILE(0, b0a, b0b, k1a, 1)
        QTILE(1, b0b, b0a, k1b, 1)
    }
    // tail tile 8 (parity 0); stages are redundant re-loads of k0=512.
    QTILE(0, b0a, b0b, 512, 0)

    asm volatile("s_waitcnt vmcnt(0)" ::: "memory");
    __builtin_amdgcn_s_barrier();

    // ------------------------------------------------------------- epilogue
    if (n0 < 1024) {
#pragma unroll
        for (int ah = 0; ah < 2; ah++)
#pragma unroll
        for (int bh = 0; bh < 2; bh++)
#pragma unroll
        for (int m_ = 0; m_ < 4; m_++)
#pragma unroll
        for (int n_ = 0; n_ < 2; n_++) {
            int lr0 = ah * 128 + wr * 64 + m_ * 16 + ((lane >> 4) << 2);
            int lc = bh * 128 + wc * 32 + n_ * 16 + (lane & 15);
            float s1c = auxp[512 + lc], s2c = auxp[768 + lc];
#pragma unroll
            for (int r_ = 0; r_ < 4; r_++) {
                int lr = lr0 + r_;
                float v = auxp[256 + lr] * (acc[ah][bh][m_][n_][r_]
                          - auxp[lr] * s1c) + s2c;
                S[lr * 256 + (lc ^ ((lr & 7) << 3))] = f2bf(v);
            }
        }
        __syncthreads();
#pragma unroll
        for (int i = 0; i < 16; i++) {
            int g = i * 512 + tid;
            int row = g >> 5, c0 = (g & 31) * 8;
            *(u16x8*)&C[(long)(m0 + row) * 1664 + n0 + c0] =
                *(const u16x8*)&S[row * 256 + (c0 ^ ((row & 7) << 3))];
        }
    } else {
        int u0 = n0 - 1024, b = m0 >> 11, nloc = m0 & 2047;
#pragma unroll
        for (int ah = 0; ah < 2; ah++)
#pragma unroll
        for (int bh = 0; bh < 2; bh++)
#pragma unroll
        for (int m_ = 0; m_ < 4; m_++)
#pragma unroll
        for (int n_ = 0; n_ < 2; n_++) {
            int lr0 = ah * 128 + wr * 64 + m_ * 16 + ((lane >> 4) << 2);
            int lc = bh * 128 + wc * 32 + n_ * 16 + (lane & 15);
            float s1c = auxp[512 + lc], s2c = auxp[768 + lc];
#pragma unroll
            for (int r_ = 0; r_ < 4; r_++) {
                int lr = lr0 + r_;
                float v = auxp[256 + lr] * (acc[ah][bh][m_][n_][r_]
                          - auxp[lr] * s1c) + s2c;
                S[lc * 256 + (lr ^ ((lc & 7) << 3))] = f2bf(v);
            }
        }
        __syncthreads();
        const u16x8 ones = {0x3F80,0x3F80,0x3F80,0x3F80,0x3F80,0x3F80,0x3F80,0x3F80};
#pragma unroll
        for (int i = 0; i < 16; i++) {
            int g = i * 512 + tid;
            int ur = g >> 5, t0 = (g & 31) * 8;
            int u = u0 + ur;
            if (u < VTROWS) {
                u16x8 vv;
                if (u == 513) vv = ones;
                else vv = *(const u16x8*)&S[ur * 256 + (t0 ^ ((ur & 7) << 3))];
                *(u16x8*)&VT[((long)b * VTROWS + u) * 2048 + nloc + t0] = vv;
            }
        }
    }
}

// ---------------------------------------------------------------------------
// GEMM C[m][n] = sum_{k<K} A[m][k]*Bt[n][k]  (+ A[m][K]*Bt[n][K] if r1).
// 128x128 tile, BK=64, 4 waves. 1-D grid, bijective XCD-chunked swizzle.
// T2 LDS XOR-swizzle (both-sides): pre-swizzled global source column for
// global_load_lds + matching XOR on ds_read_b128 fragment reads.
__global__ __launch_bounds__(256) void k_gemm_bt(
    const u16* __restrict__ A, const u16* __restrict__ Bt, u16* __restrict__ C,
    int M, int N, int K, int lda, int ldb, int ldc,
    long sA, long sB, long sC,
    const float* __restrict__ aux1, const float* __restrict__ aux2,
    const float* __restrict__ aux3, const float* __restrict__ aux4,
    long sAux, const u16* __restrict__ Res,
    float cscale, int mode, int r1, int padw,
    int ntm, int ntn, int nbz,
    u16* __restrict__ VT, int vtbase)
{
    int G = ntm * ntn * nbz;
    int id = blockIdx.x;
    int lin = (id & 7) * (G >> 3) + (id >> 3);
    int per = ntm * ntn;
    int bz = lin / per;
    int rem = lin - bz * per;
    int mt = rem / ntn;
    int nt = rem - mt * ntn;
    int m0 = mt * 128, n0 = nt * 128;

    A += (long)bz * sA; Bt += (long)bz * sB; C += (long)bz * sC;
    int tid = threadIdx.x, lane = tid & 63, w = tid >> 6;
    int wr = w >> 1, wc = w & 1;
    __shared__ u16 ldsbuf[2 * 128 * 64];      // Als | Bls; then Res/C tile
    u16* Als = ldsbuf;
    u16* Bls = ldsbuf + 128 * 64;
    __shared__ float auxR0[128], auxR1[128], auxA1[128];
    __shared__ float auxC0[128], auxC1[128], auxB1[128];

    if (tid < 128) {
        int gr = m0 + tid; if (gr >= M) gr = M - 1;
        float r0v = cscale, r1v = 0.f, a1v = 0.f;
        if (mode == 1) {
            const float* d1 = aux1 + (long)bz * sAux;
            r0v = cscale / (d1[gr] + 1e-6f);
        } else if (mode == 3) { r0v = aux1[gr]; r1v = aux2[gr]; }
        if (r1) a1v = bf2f(A[(long)gr * lda + K]);
        auxR0[tid] = r0v; auxR1[tid] = r1v; auxA1[tid] = a1v;
    } else {
        int t = tid - 128;
        int gc = n0 + t; if (gc >= N) gc = N - 1;
        float c0v = 0.f, c1v = 0.f, b1v = 0.f;
        if (mode == 3) { c0v = aux3[gc]; c1v = aux4[gc]; }
        if (r1) b1v = bf2f(Bt[(long)gc * ldb + K]);
        auxC0[t] = c0v; auxC1[t] = c1v; auxB1[t] = b1v;
    }

    f32x4 acc[4][4];
#pragma unroll
    for (int m = 0; m < 4; m++)
#pragma unroll
        for (int n = 0; n < 4; n++) { acc[m][n][0]=0.f; acc[m][n][1]=0.f; acc[m][n][2]=0.f; acc[m][n][3]=0.f; }

    int srow = lane >> 3;
    int scol = (lane & 7) * 8;
    int scolsw = scol ^ (srow << 3);
    int swz = (lane & 7) << 3;

    for (int k0 = 0; k0 < K; k0 += 64) {
#pragma unroll
        for (int i = 0; i < 4; i++) {
            int rt = (w * 4 + i) * 8 + srow;
            int gr = m0 + rt; gr = (gr < M) ? gr : (M - 1);
            gload_lds16(A + (long)gr * lda + k0 + scolsw, &Als[(w * 4 + i) * 512]);
        }
#pragma unroll
        for (int i = 0; i < 4; i++) {
            int rt = (w * 4 + i) * 8 + srow;
            int gc = n0 + rt; gc = (gc < N) ? gc : (N - 1);
            gload_lds16(Bt + (long)gc * ldb + k0 + scolsw, &Bls[(w * 4 + i) * 512]);
        }
        __syncthreads();
#pragma unroll
        for (int ks = 0; ks < 2; ks++) {
            u16x8 af[4], bfv[4];
#pragma unroll
            for (int m = 0; m < 4; m++) {
                int row = wr * 64 + m * 16 + (lane & 15);
                af[m] = *(const u16x8*)&Als[row * 64 + ((ks * 32 + (lane >> 4) * 8) ^ swz)];
            }
#pragma unroll
            for (int n = 0; n < 4; n++) {
                int col = wc * 64 + n * 16 + (lane & 15);
                bfv[n] = *(const u16x8*)&Bls[col * 64 + ((ks * 32 + (lane >> 4) * 8) ^ swz)];
            }
#pragma unroll
            for (int m = 0; m < 4; m++)
#pragma unroll
                for (int n = 0; n < 4; n++)
                    acc[m][n] = mfma_16x16x32_bf16(af[m], bfv[n], acc[m][n]);
        }
        __syncthreads();
    }
    // LDS (Als/Bls) now dead; reuse for Res/C tile.

    bool isvt = (VT != nullptr) && (n0 >= vtbase);

    if (Res) {
        const u16* Rp = Res + (long)bz * sC;
#pragma unroll
        for (int i = 0; i < 8; i++) {
            int lrow = i * 16 + (tid >> 4);
            int lcol = (tid & 15) * 8;
            long gr = m0 + lrow; if (gr > (long)M - 1) gr = M - 1;
            long gcol = (long)n0 + lcol;
            long mx = (long)ldc - 8; if (gcol > mx) gcol = mx;
            *(u16x8*)&ldsbuf[lrow * 128 + lcol] = *(const u16x8*)&Rp[gr * ldc + gcol];
        }
        __syncthreads();
    }

    asm volatile("s_nop 7\n\ts_nop 7" ::: );

    if (!isvt) {
        // normal pack: ldsbuf[row][col]
#pragma unroll
        for (int m = 0; m < 4; m++) {
            int lrbase = wr * 64 + m * 16 + ((lane >> 4) << 2);
#pragma unroll
            for (int n = 0; n < 4; n++) {
                int lc = wc * 64 + n * 16 + (lane & 15);
                float c0v = auxC0[lc], c1v = auxC1[lc], b1v = auxB1[lc];
#pragma unroll
                for (int r = 0; r < 4; r++) {
                    int lr = lrbase + r;
                    float wv = acc[m][n][r] + auxA1[lr] * b1v;
                    float v;
                    if (mode == 3) v = auxR1[lr] * (wv - auxR0[lr] * c0v) + c1v;
                    else {
                        v = wv * auxR0[lr];
                        if (Res) v += bf2f(ldsbuf[lr * 128 + lc]);
                    }
                    ldsbuf[lr * 128 + lc] = f2bf(v);
                }
            }
        }
        __syncthreads();

        int lcol = (tid & 15) * 8;
        int gc0 = n0 + lcol;
        bool colok = padw || (gc0 + 8 <= N);
#pragma unroll
        for (int i = 0; i < 8; i++) {
            int lrow = i * 16 + (tid >> 4);
            int gr = m0 + lrow;
            if (gr < M && colok) {
                *(u16x8*)&C[(long)gr * ldc + gc0] = *(const u16x8*)&ldsbuf[lrow * 128 + lcol];
            }
        }
    } else {
        // V-direct: pack transposed + XOR-swizzled: ldsbuf[u][token^((u&7)<<3)]
        int u0 = n0 - vtbase;
        int b = m0 >> 11;
        int nloc = m0 & 2047;
#pragma unroll
        for (int m = 0; m < 4; m++) {
            int lrbase = wr * 64 + m * 16 + ((lane >> 4) << 2);
#pragma unroll
            for (int n = 0; n < 4; n++) {
                int lc = wc * 64 + n * 16 + (lane & 15);
                float c0v = auxC0[lc], c1v = auxC1[lc];
#pragma unroll
                for (int r = 0; r < 4; r++) {
                    int lr = lrbase + r;
                    float wv = acc[m][n][r];
                    float v = (mode == 3) ? (auxR1[lr] * (wv - auxR0[lr] * c0v) + c1v)
                                          : (wv * auxR0[lr]);
                    ldsbuf[lc * 128 + (lr ^ ((lc & 7) << 3))] = f2bf(v);
                }
            }
        }
        __syncthreads();

        int nc = (tid & 15) * 8;          // token offset, 8-contiguous
        const u16x8 ones = {0x3F80,0x3F80,0x3F80,0x3F80,0x3F80,0x3F80,0x3F80,0x3F80};
#pragma unroll
        for (int i = 0; i < 8; i++) {
            int ur = i * 16 + (tid >> 4);
            int u = u0 + ur;
            if (u < VTROWS) {
                u16x8 vv;
                if (u == 513) vv = ones;
                else vv = *(const u16x8*)&ldsbuf[ur * 128 + (nc ^ ((ur & 7) << 3))];
                *(u16x8*)&VT[((long)b * VTROWS + u) * 2048 + nloc + nc] = vv;
            }
        }
    }
}

// ---------------------------------------------------------------------------
extern "C" void kernel_launch(void* const* d_in, const int* in_sizes, int n_in,
                              void* d_out, int out_size, void* d_ws, size_t ws_size,
                              hipStream_t stream)
{
    const float* xs    = (const float*)d_in[0];
    const float* ys    = (const float*)d_in[1];
    const float* qx    = (const float*)d_in[2];
    const float* Wq    = (const float*)d_in[3];
    const float* Wk    = (const float*)d_in[4];
    const float* Wv    = (const float*)d_in[5];
    const float* Wo    = (const float*)d_in[6];
    const float* ln1w  = (const float*)d_in[7];
    const float* ln1b  = (const float*)d_in[8];
    const float* ln2w  = (const float*)d_in[9];
    const float* ln2b  = (const float*)d_in[10];
    const float* scale = (const float*)d_in[11];
    const float* predw = (const float*)d_in[12];
    float* out = (float*)d_out;

    char* ws = (char*)d_ws;
    u16*   tok   = (u16*)(ws + 0L);              // 150,994,944
    u16*   buf1  = (u16*)(ws + 150994944L);      // 150,994,944  vt then z
    u16*   qkv   = (u16*)(ws + 301989888L);      // 436,207,616
    u16*   kpt   = (u16*)(ws + 738197504L);      // 134,217,728  Kp^T / w2t
    u16*   kvh   = (u16*)(ws + 872415232L);      //  41,943,040
    float* denom = (float*)(ws + 914358272L);
    float* meanb = (float*)(ws + 914882560L);
    float* rstdb = (float*)(ws + 915406848L);
    float* ksum  = (float*)(ws + 915931136L);
    u16*   wcat  = (u16*)(ws + 916062208L);
    u16*   wop   = (u16*)(ws + 923729920L);
    float* s1    = (float*)(ws + 926384128L);
    float* s2    = (float*)(ws + 926410752L);
    float* rkb   = (float*)(ws + 301465600L);    // tail of buf1 region
    u16*   w2t   = kpt;

    static bool attr_done = false;
    if (!attr_done) {
        (void)hipFuncSetAttribute((const void*)k_qkv8,
            hipFuncAttributeMaxDynamicSharedMemorySize, 135168);
        attr_done = true;
    }

    k_build_tokens<<<32768, 256, 0, stream>>>(xs, ys, qx, tok, meanb, rstdb);
    {
        long n1 = 4L * NQK * P;
        k_prep_wcat<<<(int)((n1 + 255) / 256), 256, 0, stream>>>(Wq, Wk, Wv, ln1w, wcat);
        long n2 = 4L * P * P;
        k_prep_wo<<<(int)((n2 + 255) / 256), 256, 0, stream>>>(Wo, wop);
        k_prep_sums<<<1664, 256, 0, stream>>>(Wq, Wk, Wv, ln1w, ln1b, s1, s2);
    }

    for (int l = 0; l < 4; l++) {
        // QKV = LN-folded GEMM (K=576); 256x256 pipelined; V tiles -> vt
        k_qkv8<<<3584, 512, 135168, stream>>>(tok, wcat + (long)l * NQK * P, qkv,
            meanb, rstdb, s1 + l * NQK, s2 + l * NQK, buf1);
        // Qp in place + rk
        k_qknorm<<<32768, 256, 0, stream>>>(qkv, rkb, scale, l);
        // Kp^T tiles only
        {
            dim3 g(8, 2048, 1);
            k_trans<<<g, 256, 0, stream>>>(qkv, rkb, kpt);
        }
        // kvh[b][h][u] = sum_n Kp[n][h] V[n][u]  (col 513 = Ksum)
        k_gemm_bt<<<1280, 256, 0, stream>>>(kpt, buf1, kvh,
            512, VTROWS, 2048, 2048, 2048, KVLD,
            512L * 2048, (long)VTROWS * 2048, 512L * KVLD,
            nullptr, nullptr, nullptr, nullptr, 0, nullptr, 1.f, 0, 0, 1,
            4, 5, 64, nullptr, 1 << 30);
        k_extract_ksum<<<64, 512, 0, stream>>>(kvh, ksum);
        k_denom<<<32768, 256, 0, stream>>>(qkv, ksum, denom);
        // w2t[b][t][h] = sum_{u<=512} Wo[t][u] kvh[b][h][u]  (K=512 + rank-1)
        k_gemm_bt<<<1280, 256, 0, stream>>>(wop + (long)l * P * P, kvh, w2t,
            576, 512, 512, P, KVLD, 512,
            0, 512L * KVLD, 576L * 512,
            nullptr, nullptr, nullptr, nullptr, 0, nullptr, 1.f, 0, 1, 0,
            5, 4, 64, nullptr, 1 << 30);
        // z = 0.1*(Qp @ w2t^T)/(denom+eps) + tok
        k_gemm_bt<<<5120, 256, 0, stream>>>(qkv, w2t, buf1,
            2048, P, 512, NQK, 512, P,
            2048L * NQK, 576L * 512, 2048L * P,
            denom, nullptr, nullptr, nullptr, 2048, tok,
            0.1f, 1, 0, 0, 16, 5, 64, nullptr, 1 << 30);
        // tok = LN2(z) + next-layer stats
        k_ln2<<<32768, 256, 0, stream>>>(buf1, tok, ln2w + l * 513, ln2b + l * 513,
                                         meanb, rstdb);
    }
    k_predict<<<64, 64, 0, stream>>>(tok, predw, out);
}

// Round 5
// 3457.243 us; speedup vs baseline: 1.0412x; 1.0410x over previous
//
#include <hip/hip_runtime.h>
#include <cstdint>
#include <cstddef>

// ---------------------------------------------------------------------------
// MultiLayerAttentionModel on MI355X (gfx950), bf16 MFMA pipeline, round 12.
// QKV reverted to round-8's 128x128 k_gemm_bt (known-good 342us). New fused
// k_qkt replaces k_qknorm + k_trans + k_extract_ksum: one pass reads Q+K,
// writes Qp in place, builds Kp in LDS, transposes to kpt, and accumulates
// ksum[b][h] via f32 atomicAdd (ksum zeroed per layer via hipMemsetAsync).
// Saves one 134MB K-section re-read + rk round-trip + 2 launches per layer.
// ---------------------------------------------------------------------------

typedef unsigned short u16;
typedef float f32x4 __attribute__((ext_vector_type(4)));
typedef unsigned short u16x8 __attribute__((ext_vector_type(8)));

#define P 576
#define NQK 1664
#define VTROWS 514
#define KVLD 640

__device__ __forceinline__ float bf2f(u16 s) {
    union { unsigned u; float f; } v; v.u = ((unsigned)s) << 16; return v.f;
}
__device__ __forceinline__ u16 f2bf(float f) {
    union { float f; unsigned u; } v; v.f = f;
    unsigned r = v.u + 0x7FFF + ((v.u >> 16) & 1);
    return (u16)(r >> 16);
}
__device__ __forceinline__ float wredsum(float v) {
#pragma unroll
    for (int o = 32; o > 0; o >>= 1) v += __shfl_xor(v, o, 64);
    return v;
}
__device__ __forceinline__ f32x4 mfma_16x16x32_bf16(u16x8 a, u16x8 b, f32x4 c) {
    asm volatile("v_mfma_f32_16x16x32_bf16 %0, %1, %2, %0"
                 : "+v"(c) : "v"(a), "v"(b));
    return c;
}
__device__ __forceinline__ void gload_lds16(const u16* g, u16* l) {
    __builtin_amdgcn_global_load_lds(
        (const __attribute__((address_space(1))) void*)g,
        (__attribute__((address_space(3))) void*)l, 16, 0, 0);
}

// ---------------------------------------------------------------------------
__global__ __launch_bounds__(256) void k_build_tokens(
    const float* __restrict__ xs, const float* __restrict__ ys,
    const float* __restrict__ qx, u16* __restrict__ tok,
    float* __restrict__ meanb, float* __restrict__ rstdb)
{
    long row = (long)blockIdx.x * 4 + (threadIdx.x >> 6);
    int lane = threadIdx.x & 63;
    int b = (int)(row >> 11), n = (int)(row & 2047);
    const float* src = (n < 2047) ? xs + ((long)(b * 2047 + n)) * 512
                                  : qx + (long)b * 512;
    float4 f0 = *(const float4*)(src + lane * 8);
    float4 f1 = *(const float4*)(src + lane * 8 + 4);
    float y = (n < 2047) ? ys[(long)b * 2047 + n] : 0.f;
    float v[8] = {f0.x, f0.y, f0.z, f0.w, f1.x, f1.y, f1.z, f1.w};
    float s = 0.f, sq = 0.f;
#pragma unroll
    for (int j = 0; j < 8; j++) { s += v[j]; sq += v[j] * v[j]; }
    if (lane == 0) { s += y; sq += y * y; }
    s = wredsum(s); sq = wredsum(sq);
    u16x8 o;
#pragma unroll
    for (int j = 0; j < 8; j++) o[j] = f2bf(v[j]);
    *(u16x8*)(tok + row * P + lane * 8) = o;
    if (lane < 8) {
        u16x8 z8 = {0,0,0,0,0,0,0,0};
        if (lane == 0) z8[0] = f2bf(y);
        *(u16x8*)(tok + row * P + 512 + lane * 8) = z8;
    }
    if (lane == 0) {
        float m = s * (1.f / 513.f);
        float var = sq * (1.f / 513.f) - m * m;
        meanb[row] = m;
        rstdb[row] = 1.f / sqrtf(var + 1e-5f);
    }
}

__global__ __launch_bounds__(256) void k_prep_wcat(
    const float* __restrict__ wq, const float* __restrict__ wk,
    const float* __restrict__ wv, const float* __restrict__ ln1w,
    u16* __restrict__ wcat)
{
    long idx = (long)blockIdx.x * 256 + threadIdx.x;
    if (idx >= 4L * NQK * P) return;
    int t = (int)(idx % P);
    long rem = idx / P;
    int r = (int)(rem % NQK);
    int l = (int)(rem / NQK);
    float v = 0.f;
    if (t < 513) {
        float wsc = ln1w[l * 513 + t];
        if (r < 512)       v = wq[((long)l * 512 + r) * 513 + t] * wsc;
        else if (r < 1024) v = wk[((long)l * 512 + (r - 512)) * 513 + t] * wsc;
        else if (r < 1537) v = wv[((long)l * 513 + (r - 1024)) * 513 + t] * wsc;
    }
    wcat[idx] = f2bf(v);
}

__global__ __launch_bounds__(256) void k_prep_wo(
    const float* __restrict__ wo, u16* __restrict__ wop)
{
    long idx = (long)blockIdx.x * 256 + threadIdx.x;
    if (idx >= 4L * P * P) return;
    int u = (int)(idx % P);
    long rem = idx / P;
    int t = (int)(rem % P);
    int l = (int)(rem / P);
    float v = (t < 513 && u < 513) ? wo[((long)l * 513 + t) * 513 + u] : 0.f;
    wop[idx] = f2bf(v);
}

__global__ __launch_bounds__(256) void k_prep_sums(
    const float* __restrict__ wq, const float* __restrict__ wk,
    const float* __restrict__ wv, const float* __restrict__ ln1w,
    const float* __restrict__ ln1b, float* __restrict__ s1, float* __restrict__ s2)
{
    int id = blockIdx.x * 4 + (threadIdx.x >> 6);
    int lane = threadIdx.x & 63;
    int l = id / NQK, r = id % NQK;
    float a1 = 0.f, a2 = 0.f;
    for (int t = lane; t < 513; t += 64) {
        float wc = 0.f;
        if (r < 512)       wc = wq[((long)l * 512 + r) * 513 + t];
        else if (r < 1024) wc = wk[((long)l * 512 + (r - 512)) * 513 + t];
        else if (r < 1537) wc = wv[((long)l * 513 + (r - 1024)) * 513 + t];
        a1 += ln1w[l * 513 + t] * wc;
        a2 += ln1b[l * 513 + t] * wc;
    }
    a1 = wredsum(a1); a2 = wredsum(a2);
    if (lane == 0) { s1[id] = a1; s2[id] = a2; }
}

// ---------------------------------------------------------------------------
__global__ __launch_bounds__(256) void k_ln2(
    const u16* __restrict__ z, u16* __restrict__ tok,
    const float* __restrict__ w, const float* __restrict__ bia,
    float* __restrict__ meanb, float* __restrict__ rstdb)
{
    long row = (long)blockIdx.x * 4 + (threadIdx.x >> 6);
    int lane = threadIdx.x & 63;
    const u16* zp = z + row * P;
    u16* tp = tok + row * P;
    u16x8 a0 = *(const u16x8*)(zp + lane * 8);
    u16x8 a1 = {0,0,0,0,0,0,0,0};
    if (lane < 8) a1 = *(const u16x8*)(zp + 512 + lane * 8);
    float v0[8], v1[8];
#pragma unroll
    for (int j = 0; j < 8; j++) v0[j] = bf2f(a0[j]);
#pragma unroll
    for (int j = 0; j < 8; j++) v1[j] = (lane < 8) ? bf2f(a1[j]) : 0.f;
    float s = 0.f, sq = 0.f;
#pragma unroll
    for (int j = 0; j < 8; j++) { s += v0[j]; sq += v0[j] * v0[j]; }
#pragma unroll
    for (int j = 0; j < 8; j++) { s += v1[j]; sq += v1[j] * v1[j]; }
    s = wredsum(s); sq = wredsum(sq);
    float mean = s * (1.f / 513.f);
    float var = sq * (1.f / 513.f) - mean * mean;
    float rstd = 1.f / sqrtf(var + 1e-5f);
    float so = 0.f, so2 = 0.f;
    u16x8 o0;
    float of0[8];
#pragma unroll
    for (int j = 0; j < 8; j++) {
        int t = lane * 8 + j;
        of0[j] = (v0[j] - mean) * rstd * w[t] + bia[t];
        so += of0[j]; so2 += of0[j] * of0[j];
        o0[j] = f2bf(of0[j]);
    }
    float of1[8];
#pragma unroll
    for (int j = 0; j < 8; j++) {
        int t = 512 + lane * 8 + j;
        float ov = 0.f;
        if (lane < 8 && t < 513) ov = (v1[j] - mean) * rstd * w[t] + bia[t];
        of1[j] = ov;
        so += ov; so2 += ov * ov;
    }
    so = wredsum(so); so2 = wredsum(so2);
    *(u16x8*)(tp + lane * 8) = o0;
    if (lane < 8) {
        u16x8 o1;
#pragma unroll
        for (int j = 0; j < 8; j++) o1[j] = f2bf(of1[j]);
        *(u16x8*)(tp + 512 + lane * 8) = o1;
    }
    if (lane == 0) {
        float m2 = so * (1.f / 513.f);
        float v2 = so2 * (1.f / 513.f) - m2 * m2;
        meanb[row] = m2;
        rstdb[row] = 1.f / sqrtf(v2 + 1e-5f);
    }
}

// ---------------------------------------------------------------------------
// Fused qknorm + K-transpose + ksum. One block = 64 rows of one batch.
// Phase 1: per-row L2 norms of Q,K; Qp=(elu(q*rnq)+1)*s written in place;
//          Kp=elu(k*rnk)+1 -> LDS [64][520] (row-major, conflict-free).
// Phase 2: 8 column-tiles: LDS transpose (k_trans pattern) -> kpt[b][h][n];
//          per-h partial sums atomicAdd into ksum[b][h] (f32, pre-zeroed).
__global__ __launch_bounds__(256) void k_qkt(
    u16* __restrict__ qkv, u16* __restrict__ kpt,
    float* __restrict__ ksum, const float* __restrict__ scale, int l)
{
    long row0 = (long)blockIdx.x * 64;
    int b = (int)(row0 >> 11);
    int nloc = (int)(row0 & 2047);
    int tid = threadIdx.x, lane = tid & 63, w = tid >> 6;
    float s = log1pf(expf(scale[l]));
    __shared__ u16 Kp[64][520];
    __shared__ u16 T2[64 * 80];

#pragma unroll 4
    for (int i = 0; i < 16; i++) {
        int rl = w * 16 + i;
        u16* rp = qkv + (row0 + rl) * NQK;
        u16x8 q8 = *(const u16x8*)(rp + lane * 8);
        u16x8 k8 = *(const u16x8*)(rp + 512 + lane * 8);
        float qf[8], kf[8];
        float sq = 0.f, sk = 0.f;
#pragma unroll
        for (int j = 0; j < 8; j++) { qf[j] = bf2f(q8[j]); sq += qf[j] * qf[j]; }
#pragma unroll
        for (int j = 0; j < 8; j++) { kf[j] = bf2f(k8[j]); sk += kf[j] * kf[j]; }
        sq = wredsum(sq); sk = wredsum(sk);
        float rnq = 1.f / fmaxf(sqrtf(sq), 1e-12f);
        float rnk = 1.f / fmaxf(sqrtf(sk), 1e-12f);
        u16x8 o, kk;
#pragma unroll
        for (int j = 0; j < 8; j++) {
            float q = qf[j] * rnq;
            float qp = (q > 0.f) ? (q + 1.f) : expf(q);
            o[j] = f2bf(qp * s);
            float kv = kf[j] * rnk;
            kv = (kv > 0.f) ? (kv + 1.f) : expf(kv);
            kk[j] = f2bf(kv);
        }
        *(u16x8*)(rp + lane * 8) = o;
        *(u16x8*)&Kp[rl][lane * 8] = kk;
    }
    __syncthreads();

    int r = tid >> 2;
    int c0 = (tid & 3) * 16;
    for (int ct = 0; ct < 8; ct++) {
        u16x8 a = *(const u16x8*)&Kp[r][ct * 64 + c0];
        u16x8 d = *(const u16x8*)&Kp[r][ct * 64 + c0 + 8];
#pragma unroll
        for (int j = 0; j < 8; j++) T2[(c0 + j) * 80 + r] = a[j];
#pragma unroll
        for (int j = 0; j < 8; j++) T2[(c0 + 8 + j) * 80 + r] = d[j];
        __syncthreads();
        u16x8 w0 = *(const u16x8*)&T2[r * 80 + c0];
        u16x8 w1 = *(const u16x8*)&T2[r * 80 + c0 + 8];
        u16* dst = kpt + ((long)(b * 512 + ct * 64 + r)) * 2048 + nloc + c0;
        *(u16x8*)dst = w0;
        *(u16x8*)(dst + 8) = w1;
        float part = 0.f;
#pragma unroll
        for (int j = 0; j < 8; j++) part += bf2f(w0[j]) + bf2f(w1[j]);
        part += __shfl_xor(part, 1, 64);
        part += __shfl_xor(part, 2, 64);
        if ((tid & 3) == 0)
            atomicAdd(&ksum[(long)b * 512 + ct * 64 + r], part);
        __syncthreads();
    }
}

// ---------------------------------------------------------------------------
__global__ __launch_bounds__(256) void k_denom(
    const u16* __restrict__ qkv, const float* __restrict__ ksum,
    float* __restrict__ denom)
{
    long row = (long)blockIdx.x * 4 + (threadIdx.x >> 6);
    int lane = threadIdx.x & 63;
    int b = (int)(row >> 11);
    u16x8 q = *(const u16x8*)(qkv + row * NQK + lane * 8);
    const float* ks = ksum + (long)b * 512 + lane * 8;
    float acc = 0.f;
#pragma unroll
    for (int j = 0; j < 8; j++) acc += bf2f(q[j]) * ks[j];
    acc = wredsum(acc);
    if (lane == 0) denom[row] = acc;
}

__global__ void k_predict(const u16* __restrict__ tok, const float* __restrict__ pw,
                          float* __restrict__ out)
{
    int b = blockIdx.x;
    int lane = threadIdx.x;
    const u16* rp = tok + ((long)b * 2048 + 2047) * P;
    float acc = 0.f;
    for (int t = lane; t < 513; t += 64) acc += bf2f(rp[t]) * pw[t];
    acc = wredsum(acc);
    if (lane == 0) out[b] = acc;
}

// ---------------------------------------------------------------------------
// GEMM C[m][n] = sum_{k<K} A[m][k]*Bt[n][k]  (+ A[m][K]*Bt[n][K] if r1).
// 128x128 tile, BK=64, 4 waves. 1-D grid, bijective XCD-chunked swizzle.
// T2 LDS XOR-swizzle (both-sides): pre-swizzled global source column for
// global_load_lds + matching XOR on ds_read_b128 fragment reads.
__global__ __launch_bounds__(256) void k_gemm_bt(
    const u16* __restrict__ A, const u16* __restrict__ Bt, u16* __restrict__ C,
    int M, int N, int K, int lda, int ldb, int ldc,
    long sA, long sB, long sC,
    const float* __restrict__ aux1, const float* __restrict__ aux2,
    const float* __restrict__ aux3, const float* __restrict__ aux4,
    long sAux, const u16* __restrict__ Res,
    float cscale, int mode, int r1, int padw,
    int ntm, int ntn, int nbz,
    u16* __restrict__ VT, int vtbase)
{
    int G = ntm * ntn * nbz;
    int id = blockIdx.x;
    int lin = (id & 7) * (G >> 3) + (id >> 3);
    int per = ntm * ntn;
    int bz = lin / per;
    int rem = lin - bz * per;
    int mt = rem / ntn;
    int nt = rem - mt * ntn;
    int m0 = mt * 128, n0 = nt * 128;

    A += (long)bz * sA; Bt += (long)bz * sB; C += (long)bz * sC;
    int tid = threadIdx.x, lane = tid & 63, w = tid >> 6;
    int wr = w >> 1, wc = w & 1;
    __shared__ u16 ldsbuf[2 * 128 * 64];      // Als | Bls; then Res/C tile
    u16* Als = ldsbuf;
    u16* Bls = ldsbuf + 128 * 64;
    __shared__ float auxR0[128], auxR1[128], auxA1[128];
    __shared__ float auxC0[128], auxC1[128], auxB1[128];

    if (tid < 128) {
        int gr = m0 + tid; if (gr >= M) gr = M - 1;
        float r0v = cscale, r1v = 0.f, a1v = 0.f;
        if (mode == 1) {
            const float* d1 = aux1 + (long)bz * sAux;
            r0v = cscale / (d1[gr] + 1e-6f);
        } else if (mode == 3) { r0v = aux1[gr]; r1v = aux2[gr]; }
        if (r1) a1v = bf2f(A[(long)gr * lda + K]);
        auxR0[tid] = r0v; auxR1[tid] = r1v; auxA1[tid] = a1v;
    } else {
        int t = tid - 128;
        int gc = n0 + t; if (gc >= N) gc = N - 1;
        float c0v = 0.f, c1v = 0.f, b1v = 0.f;
        if (mode == 3) { c0v = aux3[gc]; c1v = aux4[gc]; }
        if (r1) b1v = bf2f(Bt[(long)gc * ldb + K]);
        auxC0[t] = c0v; auxC1[t] = c1v; auxB1[t] = b1v;
    }

    f32x4 acc[4][4];
#pragma unroll
    for (int m = 0; m < 4; m++)
#pragma unroll
        for (int n = 0; n < 4; n++) { acc[m][n][0]=0.f; acc[m][n][1]=0.f; acc[m][n][2]=0.f; acc[m][n][3]=0.f; }

    int srow = lane >> 3;
    int scol = (lane & 7) * 8;
    int scolsw = scol ^ (srow << 3);
    int swz = (lane & 7) << 3;

    for (int k0 = 0; k0 < K; k0 += 64) {
#pragma unroll
        for (int i = 0; i < 4; i++) {
            int rt = (w * 4 + i) * 8 + srow;
            int gr = m0 + rt; gr = (gr < M) ? gr : (M - 1);
            gload_lds16(A + (long)gr * lda + k0 + scolsw, &Als[(w * 4 + i) * 512]);
        }
#pragma unroll
        for (int i = 0; i < 4; i++) {
            int rt = (w * 4 + i) * 8 + srow;
            int gc = n0 + rt; gc = (gc < N) ? gc : (N - 1);
            gload_lds16(Bt + (long)gc * ldb + k0 + scolsw, &Bls[(w * 4 + i) * 512]);
        }
        __syncthreads();
#pragma unroll
        for (int ks = 0; ks < 2; ks++) {
            u16x8 af[4], bfv[4];
#pragma unroll
            for (int m = 0; m < 4; m++) {
                int row = wr * 64 + m * 16 + (lane & 15);
                af[m] = *(const u16x8*)&Als[row * 64 + ((ks * 32 + (lane >> 4) * 8) ^ swz)];
            }
#pragma unroll
            for (int n = 0; n < 4; n++) {
                int col = wc * 64 + n * 16 + (lane & 15);
                bfv[n] = *(const u16x8*)&Bls[col * 64 + ((ks * 32 + (lane >> 4) * 8) ^ swz)];
            }
#pragma unroll
            for (int m = 0; m < 4; m++)
#pragma unroll
                for (int n = 0; n < 4; n++)
                    acc[m][n] = mfma_16x16x32_bf16(af[m], bfv[n], acc[m][n]);
        }
        __syncthreads();
    }
    // LDS (Als/Bls) now dead; reuse for Res/C tile.

    bool isvt = (VT != nullptr) && (n0 >= vtbase);

    if (Res) {
        const u16* Rp = Res + (long)bz * sC;
#pragma unroll
        for (int i = 0; i < 8; i++) {
            int lrow = i * 16 + (tid >> 4);
            int lcol = (tid & 15) * 8;
            long gr = m0 + lrow; if (gr > (long)M - 1) gr = M - 1;
            long gcol = (long)n0 + lcol;
            long mx = (long)ldc - 8; if (gcol > mx) gcol = mx;
            *(u16x8*)&ldsbuf[lrow * 128 + lcol] = *(const u16x8*)&Rp[gr * ldc + gcol];
        }
        __syncthreads();
    }

    asm volatile("s_nop 7\n\ts_nop 7" ::: );

    if (!isvt) {
        // normal pack: ldsbuf[row][col]
#pragma unroll
        for (int m = 0; m < 4; m++) {
            int lrbase = wr * 64 + m * 16 + ((lane >> 4) << 2);
#pragma unroll
            for (int n = 0; n < 4; n++) {
                int lc = wc * 64 + n * 16 + (lane & 15);
                float c0v = auxC0[lc], c1v = auxC1[lc], b1v = auxB1[lc];
#pragma unroll
                for (int r = 0; r < 4; r++) {
                    int lr = lrbase + r;
                    float wv = acc[m][n][r] + auxA1[lr] * b1v;
                    float v;
                    if (mode == 3) v = auxR1[lr] * (wv - auxR0[lr] * c0v) + c1v;
                    else {
                        v = wv * auxR0[lr];
                        if (Res) v += bf2f(ldsbuf[lr * 128 + lc]);
                    }
                    ldsbuf[lr * 128 + lc] = f2bf(v);
                }
            }
        }
        __syncthreads();

        int lcol = (tid & 15) * 8;
        int gc0 = n0 + lcol;
        bool colok = padw || (gc0 + 8 <= N);
#pragma unroll
        for (int i = 0; i < 8; i++) {
            int lrow = i * 16 + (tid >> 4);
            int gr = m0 + lrow;
            if (gr < M && colok) {
                *(u16x8*)&C[(long)gr * ldc + gc0] = *(const u16x8*)&ldsbuf[lrow * 128 + lcol];
            }
        }
    } else {
        // V-direct: pack transposed + XOR-swizzled: ldsbuf[u][token^((u&7)<<3)]
        int u0 = n0 - vtbase;
        int b = m0 >> 11;
        int nloc = m0 & 2047;
#pragma unroll
        for (int m = 0; m < 4; m++) {
            int lrbase = wr * 64 + m * 16 + ((lane >> 4) << 2);
#pragma unroll
            for (int n = 0; n < 4; n++) {
                int lc = wc * 64 + n * 16 + (lane & 15);
                float c0v = auxC0[lc], c1v = auxC1[lc];
#pragma unroll
                for (int r = 0; r < 4; r++) {
                    int lr = lrbase + r;
                    float wv = acc[m][n][r];
                    float v = (mode == 3) ? (auxR1[lr] * (wv - auxR0[lr] * c0v) + c1v)
                                          : (wv * auxR0[lr]);
                    ldsbuf[lc * 128 + (lr ^ ((lc & 7) << 3))] = f2bf(v);
                }
            }
        }
        __syncthreads();

        int nc = (tid & 15) * 8;          // token offset, 8-contiguous
        const u16x8 ones = {0x3F80,0x3F80,0x3F80,0x3F80,0x3F80,0x3F80,0x3F80,0x3F80};
#pragma unroll
        for (int i = 0; i < 8; i++) {
            int ur = i * 16 + (tid >> 4);
            int u = u0 + ur;
            if (u < VTROWS) {
                u16x8 vv;
                if (u == 513) vv = ones;
                else vv = *(const u16x8*)&ldsbuf[ur * 128 + (nc ^ ((ur & 7) << 3))];
                *(u16x8*)&VT[((long)b * VTROWS + u) * 2048 + nloc + nc] = vv;
            }
        }
    }
}

// ---------------------------------------------------------------------------
extern "C" void kernel_launch(void* const* d_in, const int* in_sizes, int n_in,
                              void* d_out, int out_size, void* d_ws, size_t ws_size,
                              hipStream_t stream)
{
    const float* xs    = (const float*)d_in[0];
    const float* ys    = (const float*)d_in[1];
    const float* qx    = (const float*)d_in[2];
    const float* Wq    = (const float*)d_in[3];
    const float* Wk    = (const float*)d_in[4];
    const float* Wv    = (const float*)d_in[5];
    const float* Wo    = (const float*)d_in[6];
    const float* ln1w  = (const float*)d_in[7];
    const float* ln1b  = (const float*)d_in[8];
    const float* ln2w  = (const float*)d_in[9];
    const float* ln2b  = (const float*)d_in[10];
    const float* scale = (const float*)d_in[11];
    const float* predw = (const float*)d_in[12];
    float* out = (float*)d_out;

    char* ws = (char*)d_ws;
    u16*   tok   = (u16*)(ws + 0L);              // 150,994,944
    u16*   buf1  = (u16*)(ws + 150994944L);      // 150,994,944  vt then z
    u16*   qkv   = (u16*)(ws + 301989888L);      // 436,207,616
    u16*   kpt   = (u16*)(ws + 738197504L);      // 134,217,728  Kp^T / w2t
    u16*   kvh   = (u16*)(ws + 872415232L);      //  41,943,040
    float* denom = (float*)(ws + 914358272L);
    float* meanb = (float*)(ws + 914882560L);
    float* rstdb = (float*)(ws + 915406848L);
    float* ksum  = (float*)(ws + 915931136L);
    u16*   wcat  = (u16*)(ws + 916062208L);
    u16*   wop   = (u16*)(ws + 923729920L);
    float* s1    = (float*)(ws + 926384128L);
    float* s2    = (float*)(ws + 926410752L);
    u16*   w2t   = kpt;

    k_build_tokens<<<32768, 256, 0, stream>>>(xs, ys, qx, tok, meanb, rstdb);
    {
        long n1 = 4L * NQK * P;
        k_prep_wcat<<<(int)((n1 + 255) / 256), 256, 0, stream>>>(Wq, Wk, Wv, ln1w, wcat);
        long n2 = 4L * P * P;
        k_prep_wo<<<(int)((n2 + 255) / 256), 256, 0, stream>>>(Wo, wop);
        k_prep_sums<<<1664, 256, 0, stream>>>(Wq, Wk, Wv, ln1w, ln1b, s1, s2);
    }

    for (int l = 0; l < 4; l++) {
        hipMemsetAsync(ksum, 0, 64 * 512 * sizeof(float), stream);
        // QKV = LN-folded GEMM (K=576); V tiles (n0>=1024) go transposed to vt
        k_gemm_bt<<<13312, 256, 0, stream>>>(tok, wcat + (long)l * NQK * P, qkv,
            131072, NQK, 576, P, P, NQK, 0, 0, 0,
            meanb, rstdb, s1 + l * NQK, s2 + l * NQK, 0, nullptr,
            1.f, 3, 0, 0, 1024, 13, 1,
            buf1, 1024);
        // fused: Qp in place + Kp^T + ksum (atomics)
        k_qkt<<<2048, 256, 0, stream>>>(qkv, kpt, ksum, scale, l);
        // kvh[b][h][u] = sum_n Kp[n][h] V[n][u]
        k_gemm_bt<<<1280, 256, 0, stream>>>(kpt, buf1, kvh,
            512, VTROWS, 2048, 2048, 2048, KVLD,
            512L * 2048, (long)VTROWS * 2048, 512L * KVLD,
            nullptr, nullptr, nullptr, nullptr, 0, nullptr, 1.f, 0, 0, 1,
            4, 5, 64, nullptr, 1 << 30);
        k_denom<<<32768, 256, 0, stream>>>(qkv, ksum, denom);
        // w2t[b][t][h] = sum_{u<=512} Wo[t][u] kvh[b][h][u]  (K=512 + rank-1)
        k_gemm_bt<<<1280, 256, 0, stream>>>(wop + (long)l * P * P, kvh, w2t,
            576, 512, 512, P, KVLD, 512,
            0, 512L * KVLD, 576L * 512,
            nullptr, nullptr, nullptr, nullptr, 0, nullptr, 1.f, 0, 1, 0,
            5, 4, 64, nullptr, 1 << 30);
        // z = 0.1*(Qp @ w2t^T)/(denom+eps) + tok
        k_gemm_bt<<<5120, 256, 0, stream>>>(qkv, w2t, buf1,
            2048, P, 512, NQK, 512, P,
            2048L * NQK, 576L * 512, 2048L * P,
            denom, nullptr, nullptr, nullptr, 2048, tok,
            0.1f, 1, 0, 0, 16, 5, 64, nullptr, 1 << 30);
        // tok = LN2(z) + next-layer stats
        k_ln2<<<32768, 256, 0, stream>>>(buf1, tok, ln2w + l * 513, ln2b + l * 513,
                                         meanb, rstdb);
    }
    k_predict<<<64, 64, 0, stream>>>(tok, predw, out);
}

// Round 6
// 3441.938 us; speedup vs baseline: 1.0459x; 1.0044x over previous
//
#include <hip/hip_runtime.h>
#include <cstdint>
#include <cstddef>

// ---------------------------------------------------------------------------
// MultiLayerAttentionModel on MI355X (gfx950), bf16 MFMA pipeline, round 13.
// Round 12 + QKV GEMM runs K=512 with rank-1 correction (column 512 = y/bias
// column) instead of K=576 with 63 zero columns: 8 K-iterations instead of 9.
// k_gemm_bt V-direct epilogue branch now applies the rank-1 term too.
// ---------------------------------------------------------------------------

typedef unsigned short u16;
typedef float f32x4 __attribute__((ext_vector_type(4)));
typedef unsigned short u16x8 __attribute__((ext_vector_type(8)));

#define P 576
#define NQK 1664
#define VTROWS 514
#define KVLD 640

__device__ __forceinline__ float bf2f(u16 s) {
    union { unsigned u; float f; } v; v.u = ((unsigned)s) << 16; return v.f;
}
__device__ __forceinline__ u16 f2bf(float f) {
    union { float f; unsigned u; } v; v.f = f;
    unsigned r = v.u + 0x7FFF + ((v.u >> 16) & 1);
    return (u16)(r >> 16);
}
__device__ __forceinline__ float wredsum(float v) {
#pragma unroll
    for (int o = 32; o > 0; o >>= 1) v += __shfl_xor(v, o, 64);
    return v;
}
__device__ __forceinline__ f32x4 mfma_16x16x32_bf16(u16x8 a, u16x8 b, f32x4 c) {
    asm volatile("v_mfma_f32_16x16x32_bf16 %0, %1, %2, %0"
                 : "+v"(c) : "v"(a), "v"(b));
    return c;
}
__device__ __forceinline__ void gload_lds16(const u16* g, u16* l) {
    __builtin_amdgcn_global_load_lds(
        (const __attribute__((address_space(1))) void*)g,
        (__attribute__((address_space(3))) void*)l, 16, 0, 0);
}

// ---------------------------------------------------------------------------
__global__ __launch_bounds__(256) void k_build_tokens(
    const float* __restrict__ xs, const float* __restrict__ ys,
    const float* __restrict__ qx, u16* __restrict__ tok,
    float* __restrict__ meanb, float* __restrict__ rstdb)
{
    long row = (long)blockIdx.x * 4 + (threadIdx.x >> 6);
    int lane = threadIdx.x & 63;
    int b = (int)(row >> 11), n = (int)(row & 2047);
    const float* src = (n < 2047) ? xs + ((long)(b * 2047 + n)) * 512
                                  : qx + (long)b * 512;
    float4 f0 = *(const float4*)(src + lane * 8);
    float4 f1 = *(const float4*)(src + lane * 8 + 4);
    float y = (n < 2047) ? ys[(long)b * 2047 + n] : 0.f;
    float v[8] = {f0.x, f0.y, f0.z, f0.w, f1.x, f1.y, f1.z, f1.w};
    float s = 0.f, sq = 0.f;
#pragma unroll
    for (int j = 0; j < 8; j++) { s += v[j]; sq += v[j] * v[j]; }
    if (lane == 0) { s += y; sq += y * y; }
    s = wredsum(s); sq = wredsum(sq);
    u16x8 o;
#pragma unroll
    for (int j = 0; j < 8; j++) o[j] = f2bf(v[j]);
    *(u16x8*)(tok + row * P + lane * 8) = o;
    if (lane < 8) {
        u16x8 z8 = {0,0,0,0,0,0,0,0};
        if (lane == 0) z8[0] = f2bf(y);
        *(u16x8*)(tok + row * P + 512 + lane * 8) = z8;
    }
    if (lane == 0) {
        float m = s * (1.f / 513.f);
        float var = sq * (1.f / 513.f) - m * m;
        meanb[row] = m;
        rstdb[row] = 1.f / sqrtf(var + 1e-5f);
    }
}

__global__ __launch_bounds__(256) void k_prep_wcat(
    const float* __restrict__ wq, const float* __restrict__ wk,
    const float* __restrict__ wv, const float* __restrict__ ln1w,
    u16* __restrict__ wcat)
{
    long idx = (long)blockIdx.x * 256 + threadIdx.x;
    if (idx >= 4L * NQK * P) return;
    int t = (int)(idx % P);
    long rem = idx / P;
    int r = (int)(rem % NQK);
    int l = (int)(rem / NQK);
    float v = 0.f;
    if (t < 513) {
        float wsc = ln1w[l * 513 + t];
        if (r < 512)       v = wq[((long)l * 512 + r) * 513 + t] * wsc;
        else if (r < 1024) v = wk[((long)l * 512 + (r - 512)) * 513 + t] * wsc;
        else if (r < 1537) v = wv[((long)l * 513 + (r - 1024)) * 513 + t] * wsc;
    }
    wcat[idx] = f2bf(v);
}

__global__ __launch_bounds__(256) void k_prep_wo(
    const float* __restrict__ wo, u16* __restrict__ wop)
{
    long idx = (long)blockIdx.x * 256 + threadIdx.x;
    if (idx >= 4L * P * P) return;
    int u = (int)(idx % P);
    long rem = idx / P;
    int t = (int)(rem % P);
    int l = (int)(rem / P);
    float v = (t < 513 && u < 513) ? wo[((long)l * 513 + t) * 513 + u] : 0.f;
    wop[idx] = f2bf(v);
}

__global__ __launch_bounds__(256) void k_prep_sums(
    const float* __restrict__ wq, const float* __restrict__ wk,
    const float* __restrict__ wv, const float* __restrict__ ln1w,
    const float* __restrict__ ln1b, float* __restrict__ s1, float* __restrict__ s2)
{
    int id = blockIdx.x * 4 + (threadIdx.x >> 6);
    int lane = threadIdx.x & 63;
    int l = id / NQK, r = id % NQK;
    float a1 = 0.f, a2 = 0.f;
    for (int t = lane; t < 513; t += 64) {
        float wc = 0.f;
        if (r < 512)       wc = wq[((long)l * 512 + r) * 513 + t];
        else if (r < 1024) wc = wk[((long)l * 512 + (r - 512)) * 513 + t];
        else if (r < 1537) wc = wv[((long)l * 513 + (r - 1024)) * 513 + t];
        a1 += ln1w[l * 513 + t] * wc;
        a2 += ln1b[l * 513 + t] * wc;
    }
    a1 = wredsum(a1); a2 = wredsum(a2);
    if (lane == 0) { s1[id] = a1; s2[id] = a2; }
}

// ---------------------------------------------------------------------------
__global__ __launch_bounds__(256) void k_ln2(
    const u16* __restrict__ z, u16* __restrict__ tok,
    const float* __restrict__ w, const float* __restrict__ bia,
    float* __restrict__ meanb, float* __restrict__ rstdb)
{
    long row = (long)blockIdx.x * 4 + (threadIdx.x >> 6);
    int lane = threadIdx.x & 63;
    const u16* zp = z + row * P;
    u16* tp = tok + row * P;
    u16x8 a0 = *(const u16x8*)(zp + lane * 8);
    u16x8 a1 = {0,0,0,0,0,0,0,0};
    if (lane < 8) a1 = *(const u16x8*)(zp + 512 + lane * 8);
    float v0[8], v1[8];
#pragma unroll
    for (int j = 0; j < 8; j++) v0[j] = bf2f(a0[j]);
#pragma unroll
    for (int j = 0; j < 8; j++) v1[j] = (lane < 8) ? bf2f(a1[j]) : 0.f;
    float s = 0.f, sq = 0.f;
#pragma unroll
    for (int j = 0; j < 8; j++) { s += v0[j]; sq += v0[j] * v0[j]; }
#pragma unroll
    for (int j = 0; j < 8; j++) { s += v1[j]; sq += v1[j] * v1[j]; }
    s = wredsum(s); sq = wredsum(sq);
    float mean = s * (1.f / 513.f);
    float var = sq * (1.f / 513.f) - mean * mean;
    float rstd = 1.f / sqrtf(var + 1e-5f);
    float so = 0.f, so2 = 0.f;
    u16x8 o0;
    float of0[8];
#pragma unroll
    for (int j = 0; j < 8; j++) {
        int t = lane * 8 + j;
        of0[j] = (v0[j] - mean) * rstd * w[t] + bia[t];
        so += of0[j]; so2 += of0[j] * of0[j];
        o0[j] = f2bf(of0[j]);
    }
    float of1[8];
#pragma unroll
    for (int j = 0; j < 8; j++) {
        int t = 512 + lane * 8 + j;
        float ov = 0.f;
        if (lane < 8 && t < 513) ov = (v1[j] - mean) * rstd * w[t] + bia[t];
        of1[j] = ov;
        so += ov; so2 += ov * ov;
    }
    so = wredsum(so); so2 = wredsum(so2);
    *(u16x8*)(tp + lane * 8) = o0;
    if (lane < 8) {
        u16x8 o1;
#pragma unroll
        for (int j = 0; j < 8; j++) o1[j] = f2bf(of1[j]);
        *(u16x8*)(tp + 512 + lane * 8) = o1;
    }
    if (lane == 0) {
        float m2 = so * (1.f / 513.f);
        float v2 = so2 * (1.f / 513.f) - m2 * m2;
        meanb[row] = m2;
        rstdb[row] = 1.f / sqrtf(v2 + 1e-5f);
    }
}

// ---------------------------------------------------------------------------
// Fused qknorm + K-transpose + ksum. One block = 64 rows of one batch.
__global__ __launch_bounds__(256) void k_qkt(
    u16* __restrict__ qkv, u16* __restrict__ kpt,
    float* __restrict__ ksum, const float* __restrict__ scale, int l)
{
    long row0 = (long)blockIdx.x * 64;
    int b = (int)(row0 >> 11);
    int nloc = (int)(row0 & 2047);
    int tid = threadIdx.x, lane = tid & 63, w = tid >> 6;
    float s = log1pf(expf(scale[l]));
    __shared__ u16 Kp[64][520];
    __shared__ u16 T2[64 * 80];

#pragma unroll 4
    for (int i = 0; i < 16; i++) {
        int rl = w * 16 + i;
        u16* rp = qkv + (row0 + rl) * NQK;
        u16x8 q8 = *(const u16x8*)(rp + lane * 8);
        u16x8 k8 = *(const u16x8*)(rp + 512 + lane * 8);
        float qf[8], kf[8];
        float sq = 0.f, sk = 0.f;
#pragma unroll
        for (int j = 0; j < 8; j++) { qf[j] = bf2f(q8[j]); sq += qf[j] * qf[j]; }
#pragma unroll
        for (int j = 0; j < 8; j++) { kf[j] = bf2f(k8[j]); sk += kf[j] * kf[j]; }
        sq = wredsum(sq); sk = wredsum(sk);
        float rnq = 1.f / fmaxf(sqrtf(sq), 1e-12f);
        float rnk = 1.f / fmaxf(sqrtf(sk), 1e-12f);
        u16x8 o, kk;
#pragma unroll
        for (int j = 0; j < 8; j++) {
            float q = qf[j] * rnq;
            float qp = (q > 0.f) ? (q + 1.f) : expf(q);
            o[j] = f2bf(qp * s);
            float kv = kf[j] * rnk;
            kv = (kv > 0.f) ? (kv + 1.f) : expf(kv);
            kk[j] = f2bf(kv);
        }
        *(u16x8*)(rp + lane * 8) = o;
        *(u16x8*)&Kp[rl][lane * 8] = kk;
    }
    __syncthreads();

    int r = tid >> 2;
    int c0 = (tid & 3) * 16;
    for (int ct = 0; ct < 8; ct++) {
        u16x8 a = *(const u16x8*)&Kp[r][ct * 64 + c0];
        u16x8 d = *(const u16x8*)&Kp[r][ct * 64 + c0 + 8];
#pragma unroll
        for (int j = 0; j < 8; j++) T2[(c0 + j) * 80 + r] = a[j];
#pragma unroll
        for (int j = 0; j < 8; j++) T2[(c0 + 8 + j) * 80 + r] = d[j];
        __syncthreads();
        u16x8 w0 = *(const u16x8*)&T2[r * 80 + c0];
        u16x8 w1 = *(const u16x8*)&T2[r * 80 + c0 + 8];
        u16* dst = kpt + ((long)(b * 512 + ct * 64 + r)) * 2048 + nloc + c0;
        *(u16x8*)dst = w0;
        *(u16x8*)(dst + 8) = w1;
        float part = 0.f;
#pragma unroll
        for (int j = 0; j < 8; j++) part += bf2f(w0[j]) + bf2f(w1[j]);
        part += __shfl_xor(part, 1, 64);
        part += __shfl_xor(part, 2, 64);
        if ((tid & 3) == 0)
            atomicAdd(&ksum[(long)b * 512 + ct * 64 + r], part);
        __syncthreads();
    }
}

// ---------------------------------------------------------------------------
__global__ __launch_bounds__(256) void k_denom(
    const u16* __restrict__ qkv, const float* __restrict__ ksum,
    float* __restrict__ denom)
{
    long row = (long)blockIdx.x * 4 + (threadIdx.x >> 6);
    int lane = threadIdx.x & 63;
    int b = (int)(row >> 11);
    u16x8 q = *(const u16x8*)(qkv + row * NQK + lane * 8);
    const float* ks = ksum + (long)b * 512 + lane * 8;
    float acc = 0.f;
#pragma unroll
    for (int j = 0; j < 8; j++) acc += bf2f(q[j]) * ks[j];
    acc = wredsum(acc);
    if (lane == 0) denom[row] = acc;
}

__global__ void k_predict(const u16* __restrict__ tok, const float* __restrict__ pw,
                          float* __restrict__ out)
{
    int b = blockIdx.x;
    int lane = threadIdx.x;
    const u16* rp = tok + ((long)b * 2048 + 2047) * P;
    float acc = 0.f;
    for (int t = lane; t < 513; t += 64) acc += bf2f(rp[t]) * pw[t];
    acc = wredsum(acc);
    if (lane == 0) out[b] = acc;
}

// ---------------------------------------------------------------------------
// GEMM C[m][n] = sum_{k<K} A[m][k]*Bt[n][k]  (+ A[m][K]*Bt[n][K] if r1).
// 128x128 tile, BK=64, 4 waves. 1-D grid, bijective XCD-chunked swizzle.
// T2 LDS XOR-swizzle (both-sides): pre-swizzled global source column for
// global_load_lds + matching XOR on ds_read_b128 fragment reads.
__global__ __launch_bounds__(256) void k_gemm_bt(
    const u16* __restrict__ A, const u16* __restrict__ Bt, u16* __restrict__ C,
    int M, int N, int K, int lda, int ldb, int ldc,
    long sA, long sB, long sC,
    const float* __restrict__ aux1, const float* __restrict__ aux2,
    const float* __restrict__ aux3, const float* __restrict__ aux4,
    long sAux, const u16* __restrict__ Res,
    float cscale, int mode, int r1, int padw,
    int ntm, int ntn, int nbz,
    u16* __restrict__ VT, int vtbase)
{
    int G = ntm * ntn * nbz;
    int id = blockIdx.x;
    int lin = (id & 7) * (G >> 3) + (id >> 3);
    int per = ntm * ntn;
    int bz = lin / per;
    int rem = lin - bz * per;
    int mt = rem / ntn;
    int nt = rem - mt * ntn;
    int m0 = mt * 128, n0 = nt * 128;

    A += (long)bz * sA; Bt += (long)bz * sB; C += (long)bz * sC;
    int tid = threadIdx.x, lane = tid & 63, w = tid >> 6;
    int wr = w >> 1, wc = w & 1;
    __shared__ u16 ldsbuf[2 * 128 * 64];      // Als | Bls; then Res/C tile
    u16* Als = ldsbuf;
    u16* Bls = ldsbuf + 128 * 64;
    __shared__ float auxR0[128], auxR1[128], auxA1[128];
    __shared__ float auxC0[128], auxC1[128], auxB1[128];

    if (tid < 128) {
        int gr = m0 + tid; if (gr >= M) gr = M - 1;
        float r0v = cscale, r1v = 0.f, a1v = 0.f;
        if (mode == 1) {
            const float* d1 = aux1 + (long)bz * sAux;
            r0v = cscale / (d1[gr] + 1e-6f);
        } else if (mode == 3) { r0v = aux1[gr]; r1v = aux2[gr]; }
        if (r1) a1v = bf2f(A[(long)gr * lda + K]);
        auxR0[tid] = r0v; auxR1[tid] = r1v; auxA1[tid] = a1v;
    } else {
        int t = tid - 128;
        int gc = n0 + t; if (gc >= N) gc = N - 1;
        float c0v = 0.f, c1v = 0.f, b1v = 0.f;
        if (mode == 3) { c0v = aux3[gc]; c1v = aux4[gc]; }
        if (r1) b1v = bf2f(Bt[(long)gc * ldb + K]);
        auxC0[t] = c0v; auxC1[t] = c1v; auxB1[t] = b1v;
    }

    f32x4 acc[4][4];
#pragma unroll
    for (int m = 0; m < 4; m++)
#pragma unroll
        for (int n = 0; n < 4; n++) { acc[m][n][0]=0.f; acc[m][n][1]=0.f; acc[m][n][2]=0.f; acc[m][n][3]=0.f; }

    int srow = lane >> 3;
    int scol = (lane & 7) * 8;
    int scolsw = scol ^ (srow << 3);
    int swz = (lane & 7) << 3;

    for (int k0 = 0; k0 < K; k0 += 64) {
#pragma unroll
        for (int i = 0; i < 4; i++) {
            int rt = (w * 4 + i) * 8 + srow;
            int gr = m0 + rt; gr = (gr < M) ? gr : (M - 1);
            gload_lds16(A + (long)gr * lda + k0 + scolsw, &Als[(w * 4 + i) * 512]);
        }
#pragma unroll
        for (int i = 0; i < 4; i++) {
            int rt = (w * 4 + i) * 8 + srow;
            int gc = n0 + rt; gc = (gc < N) ? gc : (N - 1);
            gload_lds16(Bt + (long)gc * ldb + k0 + scolsw, &Bls[(w * 4 + i) * 512]);
        }
        __syncthreads();
#pragma unroll
        for (int ks = 0; ks < 2; ks++) {
            u16x8 af[4], bfv[4];
#pragma unroll
            for (int m = 0; m < 4; m++) {
                int row = wr * 64 + m * 16 + (lane & 15);
                af[m] = *(const u16x8*)&Als[row * 64 + ((ks * 32 + (lane >> 4) * 8) ^ swz)];
            }
#pragma unroll
            for (int n = 0; n < 4; n++) {
                int col = wc * 64 + n * 16 + (lane & 15);
                bfv[n] = *(const u16x8*)&Bls[col * 64 + ((ks * 32 + (lane >> 4) * 8) ^ swz)];
            }
#pragma unroll
            for (int m = 0; m < 4; m++)
#pragma unroll
                for (int n = 0; n < 4; n++)
                    acc[m][n] = mfma_16x16x32_bf16(af[m], bfv[n], acc[m][n]);
        }
        __syncthreads();
    }
    // LDS (Als/Bls) now dead; reuse for Res/C tile.

    bool isvt = (VT != nullptr) && (n0 >= vtbase);

    if (Res) {
        const u16* Rp = Res + (long)bz * sC;
#pragma unroll
        for (int i = 0; i < 8; i++) {
            int lrow = i * 16 + (tid >> 4);
            int lcol = (tid & 15) * 8;
            long gr = m0 + lrow; if (gr > (long)M - 1) gr = M - 1;
            long gcol = (long)n0 + lcol;
            long mx = (long)ldc - 8; if (gcol > mx) gcol = mx;
            *(u16x8*)&ldsbuf[lrow * 128 + lcol] = *(const u16x8*)&Rp[gr * ldc + gcol];
        }
        __syncthreads();
    }

    asm volatile("s_nop 7\n\ts_nop 7" ::: );

    if (!isvt) {
        // normal pack: ldsbuf[row][col]
#pragma unroll
        for (int m = 0; m < 4; m++) {
            int lrbase = wr * 64 + m * 16 + ((lane >> 4) << 2);
#pragma unroll
            for (int n = 0; n < 4; n++) {
                int lc = wc * 64 + n * 16 + (lane & 15);
                float c0v = auxC0[lc], c1v = auxC1[lc], b1v = auxB1[lc];
#pragma unroll
                for (int r = 0; r < 4; r++) {
                    int lr = lrbase + r;
                    float wv = acc[m][n][r] + auxA1[lr] * b1v;
                    float v;
                    if (mode == 3) v = auxR1[lr] * (wv - auxR0[lr] * c0v) + c1v;
                    else {
                        v = wv * auxR0[lr];
                        if (Res) v += bf2f(ldsbuf[lr * 128 + lc]);
                    }
                    ldsbuf[lr * 128 + lc] = f2bf(v);
                }
            }
        }
        __syncthreads();

        int lcol = (tid & 15) * 8;
        int gc0 = n0 + lcol;
        bool colok = padw || (gc0 + 8 <= N);
#pragma unroll
        for (int i = 0; i < 8; i++) {
            int lrow = i * 16 + (tid >> 4);
            int gr = m0 + lrow;
            if (gr < M && colok) {
                *(u16x8*)&C[(long)gr * ldc + gc0] = *(const u16x8*)&ldsbuf[lrow * 128 + lcol];
            }
        }
    } else {
        // V-direct: pack transposed + XOR-swizzled: ldsbuf[u][token^((u&7)<<3)]
        // (includes rank-1 term when r1 — required for K=512+r1 QKV)
        int u0 = n0 - vtbase;
        int b = m0 >> 11;
        int nloc = m0 & 2047;
#pragma unroll
        for (int m = 0; m < 4; m++) {
            int lrbase = wr * 64 + m * 16 + ((lane >> 4) << 2);
#pragma unroll
            for (int n = 0; n < 4; n++) {
                int lc = wc * 64 + n * 16 + (lane & 15);
                float c0v = auxC0[lc], c1v = auxC1[lc], b1v = auxB1[lc];
#pragma unroll
                for (int r = 0; r < 4; r++) {
                    int lr = lrbase + r;
                    float wv = acc[m][n][r] + auxA1[lr] * b1v;
                    float v = (mode == 3) ? (auxR1[lr] * (wv - auxR0[lr] * c0v) + c1v)
                                          : (wv * auxR0[lr]);
                    ldsbuf[lc * 128 + (lr ^ ((lc & 7) << 3))] = f2bf(v);
                }
            }
        }
        __syncthreads();

        int nc = (tid & 15) * 8;          // token offset, 8-contiguous
        const u16x8 ones = {0x3F80,0x3F80,0x3F80,0x3F80,0x3F80,0x3F80,0x3F80,0x3F80};
#pragma unroll
        for (int i = 0; i < 8; i++) {
            int ur = i * 16 + (tid >> 4);
            int u = u0 + ur;
            if (u < VTROWS) {
                u16x8 vv;
                if (u == 513) vv = ones;
                else vv = *(const u16x8*)&ldsbuf[ur * 128 + (nc ^ ((ur & 7) << 3))];
                *(u16x8*)&VT[((long)b * VTROWS + u) * 2048 + nloc + nc] = vv;
            }
        }
    }
}

// ---------------------------------------------------------------------------
extern "C" void kernel_launch(void* const* d_in, const int* in_sizes, int n_in,
                              void* d_out, int out_size, void* d_ws, size_t ws_size,
                              hipStream_t stream)
{
    const float* xs    = (const float*)d_in[0];
    const float* ys    = (const float*)d_in[1];
    const float* qx    = (const float*)d_in[2];
    const float* Wq    = (const float*)d_in[3];
    const float* Wk    = (const float*)d_in[4];
    const float* Wv    = (const float*)d_in[5];
    const float* Wo    = (const float*)d_in[6];
    const float* ln1w  = (const float*)d_in[7];
    const float* ln1b  = (const float*)d_in[8];
    const float* ln2w  = (const float*)d_in[9];
    const float* ln2b  = (const float*)d_in[10];
    const float* scale = (const float*)d_in[11];
    const float* predw = (const float*)d_in[12];
    float* out = (float*)d_out;

    char* ws = (char*)d_ws;
    u16*   tok   = (u16*)(ws + 0L);              // 150,994,944
    u16*   buf1  = (u16*)(ws + 150994944L);      // 150,994,944  vt then z
    u16*   qkv   = (u16*)(ws + 301989888L);      // 436,207,616
    u16*   kpt   = (u16*)(ws + 738197504L);      // 134,217,728  Kp^T / w2t
    u16*   kvh   = (u16*)(ws + 872415232L);      //  41,943,040
    float* denom = (float*)(ws + 914358272L);
    float* meanb = (float*)(ws + 914882560L);
    float* rstdb = (float*)(ws + 915406848L);
    float* ksum  = (float*)(ws + 915931136L);
    u16*   wcat  = (u16*)(ws + 916062208L);
    u16*   wop   = (u16*)(ws + 923729920L);
    float* s1    = (float*)(ws + 926384128L);
    float* s2    = (float*)(ws + 926410752L);
    u16*   w2t   = kpt;

    k_build_tokens<<<32768, 256, 0, stream>>>(xs, ys, qx, tok, meanb, rstdb);
    {
        long n1 = 4L * NQK * P;
        k_prep_wcat<<<(int)((n1 + 255) / 256), 256, 0, stream>>>(Wq, Wk, Wv, ln1w, wcat);
        long n2 = 4L * P * P;
        k_prep_wo<<<(int)((n2 + 255) / 256), 256, 0, stream>>>(Wo, wop);
        k_prep_sums<<<1664, 256, 0, stream>>>(Wq, Wk, Wv, ln1w, ln1b, s1, s2);
    }

    for (int l = 0; l < 4; l++) {
        hipMemsetAsync(ksum, 0, 64 * 512 * sizeof(float), stream);
        // QKV = LN-folded GEMM; K=512 + rank-1 (col 512); V tiles -> vt
        k_gemm_bt<<<13312, 256, 0, stream>>>(tok, wcat + (long)l * NQK * P, qkv,
            131072, NQK, 512, P, P, NQK, 0, 0, 0,
            meanb, rstdb, s1 + l * NQK, s2 + l * NQK, 0, nullptr,
            1.f, 3, 1, 0, 1024, 13, 1,
            buf1, 1024);
        // fused: Qp in place + Kp^T + ksum (atomics)
        k_qkt<<<2048, 256, 0, stream>>>(qkv, kpt, ksum, scale, l);
        // kvh[b][h][u] = sum_n Kp[n][h] V[n][u]
        k_gemm_bt<<<1280, 256, 0, stream>>>(kpt, buf1, kvh,
            512, VTROWS, 2048, 2048, 2048, KVLD,
            512L * 2048, (long)VTROWS * 2048, 512L * KVLD,
            nullptr, nullptr, nullptr, nullptr, 0, nullptr, 1.f, 0, 0, 1,
            4, 5, 64, nullptr, 1 << 30);
        k_denom<<<32768, 256, 0, stream>>>(qkv, ksum, denom);
        // w2t[b][t][h] = sum_{u<=512} Wo[t][u] kvh[b][h][u]  (K=512 + rank-1)
        k_gemm_bt<<<1280, 256, 0, stream>>>(wop + (long)l * P * P, kvh, w2t,
            576, 512, 512, P, KVLD, 512,
            0, 512L * KVLD, 576L * 512,
            nullptr, nullptr, nullptr, nullptr, 0, nullptr, 1.f, 0, 1, 0,
            5, 4, 64, nullptr, 1 << 30);
        // z = 0.1*(Qp @ w2t^T)/(denom+eps) + tok
        k_gemm_bt<<<5120, 256, 0, stream>>>(qkv, w2t, buf1,
            2048, P, 512, NQK, 512, P,
            2048L * NQK, 576L * 512, 2048L * P,
            denom, nullptr, nullptr, nullptr, 2048, tok,
            0.1f, 1, 0, 0, 16, 5, 64, nullptr, 1 << 30);
        // tok = LN2(z) + next-layer stats
        k_ln2<<<32768, 256, 0, stream>>>(buf1, tok, ln2w + l * 513, ln2b + l * 513,
                                         meanb, rstdb);
    }
    k_predict<<<64, 64, 0, stream>>>(tok, predw, out);
}